// Round 14
// baseline (403.105 us; speedup 1.0000x reference)
//
#include <hip/hip_runtime.h>
#include <hip/hip_bf16.h>

// Problem dims
#define BN 16384
#define FN 256
#define RN 32
#define CN 16
#define H1N 128
#define H2N 32
#define G1N 256
#define G2N 64

typedef __bf16 bf16_t;
typedef __bf16 bf16x8 __attribute__((ext_vector_type(8)));
typedef __bf16 bf16x4 __attribute__((ext_vector_type(4)));
typedef float f32x4 __attribute__((ext_vector_type(4)));

// ---- workspace byte offsets ----
#define OFF_DATA   0UL          // data bf16 [B][F]
#define OFF_WF1    8388608UL
#define OFF_WF2    8454144UL
#define OFF_WC1    8462336UL
#define OFF_WC2    12656640UL
#define OFF_WC3    13705216UL

// ---- LDS layout (bytes) ----
#define L_FIRE  0        // fire_s [32][33] f32 = 4224 -> pad 4352
#define L_PV    4352     // proto[256] f32 + ivar[256] f32 = 2048
#define L_DATA  6400     // mem / data tile [32][256] bf16 swz8 = 16384
#define L_C1    22784    // h1T / c1T [32][256->128] bf16 swz8 = 16384
#define L_C2    39168    // h2t / c2T [32][64] bf16 = 4096
#define L_TOT   43264

__device__ __forceinline__ f32x4 mfma16(bf16x8 a, bf16x8 b, f32x4 c) {
  return __builtin_amdgcn_mfma_f32_16x16x32_bf16(a, b, c, 0, 0, 0);
}

__device__ __forceinline__ float elu_f(float v) {
  float e = __builtin_amdgcn_exp2f(v * 1.44269504f) - 1.0f;
  return v > 0.f ? v : e;
}

// B-frag from ((row&7)<<4)-XOR-swizzled LDS tile (row stride strideB bytes).
__device__ __forceinline__ bf16x8 lfrag(const char* base, int strideB, int n0, int k0, int lane) {
  int row = n0 + (lane & 15);
  int off = (k0 * 2 + ((lane >> 4) << 4)) ^ ((row & 7) << 4);
  return *(const bf16x8*)(base + row * strideB + off);
}

// Pack W[(r,)n,k] fp32 -> 16x16x32 fragment order bf16.
__device__ __forceinline__ void pack_frag8(const float* __restrict__ src, bf16_t* __restrict__ dst,
                                           int NT, int KS, int g) {
  int per = NT * KS * 64;
  int r = g / per;
  int local = g - r * per;
  int lane = local & 63;
  int fr = local >> 6;
  int ks = fr / NT;
  int nt = fr - ks * NT;
  int N = NT * 16, K = KS * 32;
  int n = nt * 16 + (lane & 15);
  int k = ks * 32 + ((lane >> 4) << 3);
  const float* s = src + (long)r * N * K + (long)n * K + k;
  float4 a = *(const float4*)s;
  float4 b = *(const float4*)(s + 4);
  bf16x8 o;
  o[0] = (bf16_t)a.x; o[1] = (bf16_t)a.y; o[2] = (bf16_t)a.z; o[3] = (bf16_t)a.w;
  o[4] = (bf16_t)b.x; o[5] = (bf16_t)b.y; o[6] = (bf16_t)b.z; o[7] = (bf16_t)b.w;
  *(bf16x8*)(dst + (long)g * 8) = o;
}

#define G_DATA 524288
#define G_WC1  262144
#define G_WC2  65536
#define G_WF1  4096
#define G_WC3  4096
#define G_WF2  512
#define G_TOTAL (G_DATA + G_WC1 + G_WC2 + G_WF1 + G_WC3 + G_WF2)

__global__ __launch_bounds__(256) void k0_pack(
    const float* __restrict__ data, const float* __restrict__ Wf1, const float* __restrict__ Wf2,
    const float* __restrict__ Wc1, const float* __restrict__ Wc2, const float* __restrict__ Wc3,
    char* __restrict__ ws)
{
  int g = blockIdx.x * 256 + threadIdx.x;
  if (g < G_DATA) {
    const float* s = data + (long)g * 8;
    float4 a = *(const float4*)s, b = *(const float4*)(s + 4);
    bf16x8 o;
    o[0] = (bf16_t)a.x; o[1] = (bf16_t)a.y; o[2] = (bf16_t)a.z; o[3] = (bf16_t)a.w;
    o[4] = (bf16_t)b.x; o[5] = (bf16_t)b.y; o[6] = (bf16_t)b.z; o[7] = (bf16_t)b.w;
    *(bf16x8*)((bf16_t*)(ws + OFF_DATA) + (long)g * 8) = o;
    return;
  }
  g -= G_DATA;
  if (g < G_WC1) { pack_frag8(Wc1, (bf16_t*)(ws + OFF_WC1), 16, 8, g); return; }
  g -= G_WC1;
  if (g < G_WC2) { pack_frag8(Wc2, (bf16_t*)(ws + OFF_WC2), 4, 8, g); return; }
  g -= G_WC2;
  if (g < G_WF1) { pack_frag8(Wf1, (bf16_t*)(ws + OFF_WF1), 8, 8, g); return; }
  g -= G_WF1;
  if (g < G_WC3) { pack_frag8(Wc3, (bf16_t*)(ws + OFF_WC3), 1, 2, g); return; }
  g -= G_WC3;
  if (g < G_WF2) { pack_frag8(Wf2, (bf16_t*)(ws + OFF_WF2), 2, 4, g); return; }
}

// ================= MEGA KERNEL =================
// Block = one 32-row batch tile (512 blocks, 512 threads).
// Phase A: per rule, membership (data from regs) -> h1 -> h2 -> fs in LDS.
// Then in-block softmax -> fire (LDS + global).
// Phase B: stage bf16 data tile ONCE; per rule c1 -> c2 -> c3, accumulate
// out += fire * relu(c3) in registers. No c3buf / fsini / k2 / k4.
__global__ __launch_bounds__(512) void k_mega(
    const float* __restrict__ data, const float* __restrict__ proto, const float* __restrict__ var,
    const float* __restrict__ bf1g, const float* __restrict__ bf2g,
    const float* __restrict__ Wf3g, const float* __restrict__ bf3g,
    const bf16_t* __restrict__ Wf1p, const bf16_t* __restrict__ Wf2p,
    const bf16_t* __restrict__ datab,
    const bf16_t* __restrict__ Wc1p, const bf16_t* __restrict__ Wc2p, const bf16_t* __restrict__ Wc3p,
    const float* __restrict__ bc1, const float* __restrict__ bc2, const float* __restrict__ bc3,
    float* __restrict__ out, float* __restrict__ fire_g)
{
  __shared__ __attribute__((aligned(16))) char smem[L_TOT];
  float* fire_s  = (float*)(smem + L_FIRE);   // [32][33]
  float* proto_s = (float*)(smem + L_PV);     // [256]
  float* ivar_s  = (float*)(smem + L_PV + 1024);
  char*  dmem    = smem + L_DATA;             // [32][256] bf16 swz8
  char*  c1r     = smem + L_C1;               // h1T / c1T
  bf16_t* h2t    = (bf16_t*)(smem + L_C2);    // [32 p][32 b] (phase A)
  char*  c2r     = smem + L_C2;               // c2T [32][64] bf16 swz8 (phase B)

  const int bid = blockIdx.x;
  const int b0  = bid << 5;                   // 32-row tile
  const int tid = threadIdx.x;
  const int lane = tid & 63;
  const int w   = tid >> 6;                   // 0..7

  // data fp32 -> regs once (16 thr/row, 16 feats each)
  const int arow = tid >> 4;                  // 0..31
  const int af0  = (tid & 15) << 4;
  float4 dreg[4];
  {
    const float* dp = data + (long)(b0 + arow) * FN + af0;
    #pragma unroll
    for (int i = 0; i < 4; ++i) dreg[i] = *(const float4*)(dp + i * 4);
  }

  // ---------------- Phase A: FS chain for all rules ----------------
  for (int r = 0; r < RN; ++r) {
    __syncthreads();   // protect pv/mem/h2t from previous rule's readers
    if (tid < FN) {
      proto_s[tid] = proto[r * FN + tid];
      float v = var[r * FN + tid];
      v = fminf(fmaxf(v, 1e-4f), 0.1f);
      ivar_s[tid] = 1.4426950408889634f * 0.5f / (v * v);  // log2(e)/(2 v^2)
    }
    __syncthreads();

    { // membership from regs -> mem[b][f] bf16 swz8
      char* mrow = dmem + arow * 512;
      const int sw = (arow & 7) << 4;
      #pragma unroll
      for (int i = 0; i < 2; ++i) {
        const int f = af0 + i * 8;
        float4 x0 = dreg[i * 2];
        float4 x1 = dreg[i * 2 + 1];
        bf16x8 m; float d;
        d = x0.x - proto_s[f + 0]; m[0] = (bf16_t)__builtin_amdgcn_exp2f(-d * d * ivar_s[f + 0]);
        d = x0.y - proto_s[f + 1]; m[1] = (bf16_t)__builtin_amdgcn_exp2f(-d * d * ivar_s[f + 1]);
        d = x0.z - proto_s[f + 2]; m[2] = (bf16_t)__builtin_amdgcn_exp2f(-d * d * ivar_s[f + 2]);
        d = x0.w - proto_s[f + 3]; m[3] = (bf16_t)__builtin_amdgcn_exp2f(-d * d * ivar_s[f + 3]);
        d = x1.x - proto_s[f + 4]; m[4] = (bf16_t)__builtin_amdgcn_exp2f(-d * d * ivar_s[f + 4]);
        d = x1.y - proto_s[f + 5]; m[5] = (bf16_t)__builtin_amdgcn_exp2f(-d * d * ivar_s[f + 5]);
        d = x1.z - proto_s[f + 6]; m[6] = (bf16_t)__builtin_amdgcn_exp2f(-d * d * ivar_s[f + 6]);
        d = x1.w - proto_s[f + 7]; m[7] = (bf16_t)__builtin_amdgcn_exp2f(-d * d * ivar_s[f + 7]);
        *(bf16x8*)(mrow + ((f * 2) ^ sw)) = m;
      }
    }
    __syncthreads();

    // GEMM1: h1T[h=128][b=32] = Wf1 @ memT. 8m x 2n tiles; wave w -> m-tile w, n 0..1.
    f32x4 acc[2] = {};
    #pragma unroll
    for (int ks = 0; ks < 8; ++ks) {
      bf16x8 a = *(const bf16x8*)(Wf1p + (((ks * 8 + w) * 64 + lane)) * 8);
      #pragma unroll
      for (int j = 0; j < 2; ++j) {
        bf16x8 bb = lfrag(dmem, 512, j * 16, ks * 32, lane);
        acc[j] = mfma16(a, bb, acc[j]);
      }
    }
    // epilogue -> h1T [32 b][128 h] (c1 region; prev rule's readers done via loop-top barrier chain)
    {
      const int hb = w * 16 + ((lane >> 4) << 2);
      f32x4 bias = *(const f32x4*)(bf1g + hb);
      #pragma unroll
      for (int j = 0; j < 2; ++j) {
        const int b = j * 16 + (lane & 15);
        bf16x4 o;
        #pragma unroll
        for (int q = 0; q < 4; ++q)
          o[q] = (bf16_t)fmaxf(acc[j][q] + bias[q], 0.f);
        *(bf16x4*)(c1r + b * 256 + ((hb * 2) ^ ((b & 7) << 4))) = o;
      }
    }
    __syncthreads();

    // GEMM2: h2T[p=32][b=32] = Wf2 @ h1T. 2m x 2n = 4 tiles; waves 0..3.
    if (w < 4) {
      const int m = w >> 1;
      const int n = w & 1;
      f32x4 acc2 = {};
      #pragma unroll
      for (int ks = 0; ks < 4; ++ks) {
        bf16x8 a = *(const bf16x8*)(Wf2p + (((ks * 2 + m) * 64 + lane)) * 8);
        bf16x8 bb = lfrag(c1r, 256, n * 16, ks * 32, lane);
        acc2 = mfma16(a, bb, acc2);
      }
      const int p0 = m * 16 + ((lane >> 4) << 2);
      const int b  = n * 16 + (lane & 15);
      f32x4 bias = *(const f32x4*)(bf2g + p0);
      #pragma unroll
      for (int q = 0; q < 4; ++q)
        h2t[(p0 + q) * 32 + b] = (bf16_t)fmaxf(acc2[q] + bias[q], 0.f);
    }
    __syncthreads();

    if (tid < 32) { // fs = relu(h2 . Wf3 + bf3) -> fire_s[b][r]
      float s = bf3g[0];
      #pragma unroll
      for (int p = 0; p < H2N; ++p) s += (float)h2t[p * 32 + tid] * Wf3g[p];
      fire_s[tid * 33 + r] = fmaxf(s, 0.f);
    }
  }
  __syncthreads();

  // softmax over rules, per batch row (rows are independent; 32 threads)
  if (tid < 32) {
    float* row = fire_s + tid * 33;
    float m = row[0];
    #pragma unroll
    for (int i = 1; i < RN; ++i) m = fmaxf(m, row[i]);
    float s = 0.f;
    float e[RN];
    #pragma unroll
    for (int i = 0; i < RN; ++i) { e[i] = expf(row[i] - m); s += e[i]; }
    float inv = 1.f / s;
    #pragma unroll
    for (int i = 0; i < RN; ++i) row[i] = e[i] * inv;
  }
  __syncthreads();

  // write fire output + stage bf16 data tile (data region; membership is done)
  {
    int idx = tid;            // 1024 values, 2 per thread
    #pragma unroll
    for (int t = 0; t < 2; ++t) {
      int rr = idx >> 5, ii = idx & 31;
      fire_g[(long)(b0 + rr) * RN + ii] = fire_s[rr * 33 + ii];
      idx += 512;
    }
    const int row = tid >> 4;
    const int e0  = (tid & 15) << 4;
    const bf16_t* sp = datab + (long)(b0 + row) * FN + e0;
    char* drow = dmem + row * 512;
    const int sw = (row & 7) << 4;
    #pragma unroll
    for (int i = 0; i < 2; ++i) {
      bf16x8 v = *(const bf16x8*)(sp + i * 8);
      *(bf16x8*)(drow + (((e0 + i * 8) * 2) ^ sw)) = v;
    }
  }
  __syncthreads();

  // ---------------- Phase B: consequent chain, accumulate out in regs ----------------
  f32x4 acc_out = {};          // waves 0,1 only: out[b][c0..c0+3]
  for (int r = 0; r < RN; ++r) {
    // GEMM1: c1T[g1=256][b=32]. 16m x 2n tiles; wave w -> m {2w,2w+1}, n 0..1.
    const bf16_t* W1 = Wc1p + (long)r * G1N * FN;
    f32x4 acc[2][2] = {};
    #pragma unroll
    for (int ks = 0; ks < 8; ++ks) {
      bf16x8 a[2], bb[2];
      #pragma unroll
      for (int i = 0; i < 2; ++i)
        a[i] = *(const bf16x8*)(W1 + (((ks * 16 + w * 2 + i) * 64 + lane)) * 8);
      #pragma unroll
      for (int j = 0; j < 2; ++j)
        bb[j] = lfrag(dmem, 512, j * 16, ks * 32, lane);
      #pragma unroll
      for (int i = 0; i < 2; ++i)
        #pragma unroll
        for (int j = 0; j < 2; ++j)
          acc[i][j] = mfma16(a[i], bb[j], acc[i][j]);
    }
    // epilogue -> c1T (prev rule's GEMM2 readers passed last barrier)
    #pragma unroll
    for (int i = 0; i < 2; ++i) {
      const int g1b = (w * 2 + i) * 16 + ((lane >> 4) << 2);
      f32x4 bias = *(const f32x4*)(bc1 + r * G1N + g1b);
      #pragma unroll
      for (int j = 0; j < 2; ++j) {
        const int b = j * 16 + (lane & 15);
        bf16x4 o;
        #pragma unroll
        for (int q = 0; q < 4; ++q)
          o[q] = (bf16_t)elu_f(acc[i][j][q] + bias[q]);
        *(bf16x4*)(c1r + b * 512 + ((g1b * 2) ^ ((b & 7) << 4))) = o;
      }
    }
    __syncthreads();   // B1: c1T ready; also guarantees prev GEMM3 done with c2T

    // GEMM2: c2T[g2=64][b=32]. 4m x 2n = 8 tiles; one per wave.
    {
      const int m2 = w >> 1;
      const int n2 = w & 1;
      const bf16_t* W2 = Wc2p + (long)r * G2N * G1N;
      f32x4 acc2 = {};
      #pragma unroll
      for (int ks = 0; ks < 8; ++ks) {
        bf16x8 a = *(const bf16x8*)(W2 + (((ks * 4 + m2) * 64 + lane)) * 8);
        bf16x8 bb = lfrag(c1r, 512, n2 * 16, ks * 32, lane);
        acc2 = mfma16(a, bb, acc2);
      }
      const int g2b = m2 * 16 + ((lane >> 4) << 2);
      const int b = n2 * 16 + (lane & 15);
      f32x4 bias = *(const f32x4*)(bc2 + r * G2N + g2b);
      bf16x4 o;
      #pragma unroll
      for (int q = 0; q < 4; ++q)
        o[q] = (bf16_t)elu_f(acc2[q] + bias[q]);
      *(bf16x4*)(c2r + b * 128 + ((g2b * 2) ^ ((b & 7) << 4))) = o;
    }
    __syncthreads();   // B2: c2T ready

    // GEMM3: c3T[c=16][b=32]. 2 n-tiles; waves 0,1. K=64. Accumulate out.
    if (w < 2) {
      const bf16_t* W3 = Wc3p + (long)r * CN * G2N;
      f32x4 acc3 = {};
      #pragma unroll
      for (int ks = 0; ks < 2; ++ks) {
        bf16x8 a = *(const bf16x8*)(W3 + (((long)ks * 64 + lane)) * 8);
        bf16x8 bb = lfrag(c2r, 128, w * 16, ks * 32, lane);
        acc3 = mfma16(a, bb, acc3);
      }
      const int c0 = ((lane >> 4) << 2);
      const int b  = w * 16 + (lane & 15);
      const float fw = fire_s[b * 33 + r];
      f32x4 bias = *(const f32x4*)(bc3 + r * CN + c0);
      #pragma unroll
      for (int q = 0; q < 4; ++q)
        acc_out[q] += fw * fmaxf(acc3[q] + bias[q], 0.f);
    }
  }

  if (w < 2) {
    const int c0 = ((lane >> 4) << 2);
    const int b  = w * 16 + (lane & 15);
    *(f32x4*)(out + (long)(b0 + b) * CN + c0) = acc_out;
  }
}

extern "C" void kernel_launch(void* const* d_in, const int* in_sizes, int n_in,
                              void* d_out, int out_size, void* d_ws, size_t ws_size,
                              hipStream_t stream) {
  const float* data = (const float*)d_in[0];
  const float* proto = (const float*)d_in[1];
  const float* var  = (const float*)d_in[2];
  const float* Wf1  = (const float*)d_in[3];
  const float* bf1  = (const float*)d_in[4];
  const float* Wf2  = (const float*)d_in[5];
  const float* bf2  = (const float*)d_in[6];
  const float* Wf3  = (const float*)d_in[7];
  const float* bf3  = (const float*)d_in[8];
  const float* Wc1  = (const float*)d_in[9];
  const float* bc1  = (const float*)d_in[10];
  const float* Wc2  = (const float*)d_in[11];
  const float* bc2  = (const float*)d_in[12];
  const float* Wc3  = (const float*)d_in[13];
  const float* bc3  = (const float*)d_in[14];

  char* ws = (char*)d_ws;
  bf16_t* datab = (bf16_t*)(ws + OFF_DATA);
  bf16_t* Wf1p  = (bf16_t*)(ws + OFF_WF1);
  bf16_t* Wf2p  = (bf16_t*)(ws + OFF_WF2);
  bf16_t* Wc1p  = (bf16_t*)(ws + OFF_WC1);
  bf16_t* Wc2p  = (bf16_t*)(ws + OFF_WC2);
  bf16_t* Wc3p  = (bf16_t*)(ws + OFF_WC3);

  float* out  = (float*)d_out;               // [B][C]
  float* fire = out + (long)BN * CN;         // [B][R]

  k0_pack<<<G_TOTAL / 256, 256, 0, stream>>>(data, Wf1, Wf2, Wc1, Wc2, Wc3, ws);
  k_mega<<<BN / 32, 512, 0, stream>>>(
      data, proto, var, bf1, bf2, Wf3, bf3, Wf1p, Wf2p,
      datab, Wc1p, Wc2p, Wc3p, bc1, bc2, bc3, out, fire);
}

// Round 18
// 256.174 us; speedup vs baseline: 1.5736x; 1.5736x over previous
//
#include <hip/hip_runtime.h>
#include <hip/hip_bf16.h>

// Problem dims
#define BN 16384
#define FN 256
#define RN 32
#define CN 16
#define H1N 128
#define H2N 32
#define G1N 256
#define G2N 64

typedef __bf16 bf16_t;
typedef __bf16 bf16x8 __attribute__((ext_vector_type(8)));
typedef __bf16 bf16x4 __attribute__((ext_vector_type(4)));
typedef float f32x4 __attribute__((ext_vector_type(4)));

// ---- workspace byte offsets ----
#define OFF_DATA   0UL
#define OFF_WF1    8388608UL
#define OFF_WF2    8454144UL
#define OFF_WC1    8462336UL
#define OFF_WC2    12656640UL
#define OFF_WC3    13705216UL
#define OFF_FSINI  13770752UL
#define OFF_C3     15867904UL

__device__ __forceinline__ f32x4 mfma16(bf16x8 a, bf16x8 b, f32x4 c) {
  return __builtin_amdgcn_mfma_f32_16x16x32_bf16(a, b, c, 0, 0, 0);
}

__device__ __forceinline__ float elu_f(float v) {
  float e = __builtin_amdgcn_exp2f(v * 1.44269504f) - 1.0f;
  return v > 0.f ? v : e;
}

// B-frag from ((row&7)<<4)-XOR-swizzled LDS tile (row stride strideB bytes).
__device__ __forceinline__ bf16x8 lfrag(const char* base, int strideB, int n0, int k0, int lane) {
  int row = n0 + (lane & 15);
  int off = (k0 * 2 + ((lane >> 4) << 4)) ^ ((row & 7) << 4);
  return *(const bf16x8*)(base + row * strideB + off);
}

// Pack W[(r,)n,k] fp32 -> 16x16x32 fragment order bf16.
__device__ __forceinline__ void pack_frag8(const float* __restrict__ src, bf16_t* __restrict__ dst,
                                           int NT, int KS, int g) {
  int per = NT * KS * 64;
  int r = g / per;
  int local = g - r * per;
  int lane = local & 63;
  int fr = local >> 6;
  int ks = fr / NT;
  int nt = fr - ks * NT;
  int N = NT * 16, K = KS * 32;
  int n = nt * 16 + (lane & 15);
  int k = ks * 32 + ((lane >> 4) << 3);
  const float* s = src + (long)r * N * K + (long)n * K + k;
  float4 a = *(const float4*)s;
  float4 b = *(const float4*)(s + 4);
  bf16x8 o;
  o[0] = (bf16_t)a.x; o[1] = (bf16_t)a.y; o[2] = (bf16_t)a.z; o[3] = (bf16_t)a.w;
  o[4] = (bf16_t)b.x; o[5] = (bf16_t)b.y; o[6] = (bf16_t)b.z; o[7] = (bf16_t)b.w;
  *(bf16x8*)(dst + (long)g * 8) = o;
}

#define G_DATA 524288
#define G_WC1  262144
#define G_WC2  65536
#define G_WF1  4096
#define G_WC3  4096
#define G_WF2  512
#define G_TOTAL (G_DATA + G_WC1 + G_WC2 + G_WF1 + G_WC3 + G_WF2)

__global__ __launch_bounds__(256) void k0_pack(
    const float* __restrict__ data, const float* __restrict__ Wf1, const float* __restrict__ Wf2,
    const float* __restrict__ Wc1, const float* __restrict__ Wc2, const float* __restrict__ Wc3,
    char* __restrict__ ws)
{
  int g = blockIdx.x * 256 + threadIdx.x;
  if (g < G_DATA) {
    const float* s = data + (long)g * 8;
    float4 a = *(const float4*)s, b = *(const float4*)(s + 4);
    bf16x8 o;
    o[0] = (bf16_t)a.x; o[1] = (bf16_t)a.y; o[2] = (bf16_t)a.z; o[3] = (bf16_t)a.w;
    o[4] = (bf16_t)b.x; o[5] = (bf16_t)b.y; o[6] = (bf16_t)b.z; o[7] = (bf16_t)b.w;
    *(bf16x8*)((bf16_t*)(ws + OFF_DATA) + (long)g * 8) = o;
    return;
  }
  g -= G_DATA;
  if (g < G_WC1) { pack_frag8(Wc1, (bf16_t*)(ws + OFF_WC1), 16, 8, g); return; }
  g -= G_WC1;
  if (g < G_WC2) { pack_frag8(Wc2, (bf16_t*)(ws + OFF_WC2), 4, 8, g); return; }
  g -= G_WC2;
  if (g < G_WF1) { pack_frag8(Wf1, (bf16_t*)(ws + OFF_WF1), 8, 8, g); return; }
  g -= G_WF1;
  if (g < G_WC3) { pack_frag8(Wc3, (bf16_t*)(ws + OFF_WC3), 1, 2, g); return; }
  g -= G_WC3;
  if (g < G_WF2) { pack_frag8(Wf2, (bf16_t*)(ws + OFF_WF2), 2, 4, g); return; }
}

// ---------------- K1: FS chain, per (rule, 64-row tile). R11 lean body. ----------------
__global__ __launch_bounds__(512) void k1_fs(
    const float* __restrict__ data, const float* __restrict__ proto, const float* __restrict__ var,
    const float* __restrict__ bf1g, const float* __restrict__ bf2g,
    const float* __restrict__ Wf3g, const float* __restrict__ bf3g,
    const bf16_t* __restrict__ Wf1p, const bf16_t* __restrict__ Wf2p,
    float* __restrict__ fsini)
{
  __shared__ __attribute__((aligned(16))) char smem[38912];
  char* fs_lds   = smem;
  bf16_t* h2t    = (bf16_t*)(smem + 32768);
  float* proto_s = (float*)(smem + 36864);
  float* ivar_s  = (float*)(smem + 37888);

  const int bid = blockIdx.x;
  const int r   = bid >> 8;
  const int b0  = (bid & 255) << 6;
  const int tid = threadIdx.x;
  const int lane = tid & 63;
  const int w   = tid >> 6;

  if (tid < FN) {
    proto_s[tid] = proto[r * FN + tid];
    float v = var[r * FN + tid];
    v = fminf(fmaxf(v, 1e-4f), 0.1f);
    ivar_s[tid] = 1.4426950408889634f * 0.5f / (v * v);
  }
  __syncthreads();

  { // membership
    const int row = tid >> 3;
    const int f0  = (tid & 7) << 5;
    const float* dp = data + (long)(b0 + row) * FN + f0;
    char* mrow = fs_lds + row * 512;
    const int sw = (row & 7) << 4;
    #pragma unroll
    for (int i = 0; i < 4; ++i) {
      const int f = f0 + i * 8;
      float4 x0 = *(const float4*)(dp + i * 8);
      float4 x1 = *(const float4*)(dp + i * 8 + 4);
      bf16x8 m; float d;
      d = x0.x - proto_s[f + 0]; m[0] = (bf16_t)__builtin_amdgcn_exp2f(-d * d * ivar_s[f + 0]);
      d = x0.y - proto_s[f + 1]; m[1] = (bf16_t)__builtin_amdgcn_exp2f(-d * d * ivar_s[f + 1]);
      d = x0.z - proto_s[f + 2]; m[2] = (bf16_t)__builtin_amdgcn_exp2f(-d * d * ivar_s[f + 2]);
      d = x0.w - proto_s[f + 3]; m[3] = (bf16_t)__builtin_amdgcn_exp2f(-d * d * ivar_s[f + 3]);
      d = x1.x - proto_s[f + 4]; m[4] = (bf16_t)__builtin_amdgcn_exp2f(-d * d * ivar_s[f + 4]);
      d = x1.y - proto_s[f + 5]; m[5] = (bf16_t)__builtin_amdgcn_exp2f(-d * d * ivar_s[f + 5]);
      d = x1.z - proto_s[f + 6]; m[6] = (bf16_t)__builtin_amdgcn_exp2f(-d * d * ivar_s[f + 6]);
      d = x1.w - proto_s[f + 7]; m[7] = (bf16_t)__builtin_amdgcn_exp2f(-d * d * ivar_s[f + 7]);
      *(bf16x8*)(mrow + ((f * 2) ^ sw)) = m;
    }
  }
  __syncthreads();

  // GEMM1: h1T[128][64] = Wf1 @ memT. wave w -> m-tile w, n-tiles 0..3.
  f32x4 acc[4] = {};
  #pragma unroll
  for (int ks = 0; ks < 8; ++ks) {
    bf16x8 a = *(const bf16x8*)(Wf1p + (((ks * 8 + w) * 64 + lane)) * 8);
    #pragma unroll
    for (int j = 0; j < 4; ++j) {
      bf16x8 bb = lfrag(fs_lds, 512, j * 16, ks * 32, lane);
      acc[j] = mfma16(a, bb, acc[j]);
    }
  }
  __syncthreads();

  {
    const int hb = w * 16 + ((lane >> 4) << 2);
    f32x4 bias = *(const f32x4*)(bf1g + hb);
    #pragma unroll
    for (int j = 0; j < 4; ++j) {
      const int b = j * 16 + (lane & 15);
      bf16x4 o;
      #pragma unroll
      for (int q = 0; q < 4; ++q)
        o[q] = (bf16_t)fmaxf(acc[j][q] + bias[q], 0.f);
      *(bf16x4*)(fs_lds + b * 256 + ((hb * 2) ^ ((b & 7) << 4))) = o;
    }
  }
  __syncthreads();

  // GEMM2: h2T[32][64] = Wf2 @ h1T
  {
    const int m = w >> 2;
    const int n = w & 3;
    f32x4 acc2 = {};
    #pragma unroll
    for (int ks = 0; ks < 4; ++ks) {
      bf16x8 a = *(const bf16x8*)(Wf2p + (((ks * 2 + m) * 64 + lane)) * 8);
      bf16x8 bb = lfrag(fs_lds, 256, n * 16, ks * 32, lane);
      acc2 = mfma16(a, bb, acc2);
    }
    const int p0 = m * 16 + ((lane >> 4) << 2);
    const int b  = n * 16 + (lane & 15);
    f32x4 bias = *(const f32x4*)(bf2g + p0);
    #pragma unroll
    for (int q = 0; q < 4; ++q)
      h2t[(p0 + q) * 64 + b] = (bf16_t)fmaxf(acc2[q] + bias[q], 0.f);
  }
  __syncthreads();

  if (tid < 64) {
    float s = bf3g[0];
    #pragma unroll
    for (int p = 0; p < H2N; ++p) s += (float)h2t[p * 64 + tid] * Wf3g[p];
    fsini[(long)(b0 + tid) * RN + r] = fmaxf(s, 0.f);
  }
}

// ---------------- K3: consequent chain, 2 rules per block, data staged once ----------------
// LDS: data 32KB (persistent) + c1T 32KB + c2T 8KB = 72KB -> 2 blocks/CU (measured neutral vs 4).
// GEMM layouts identical to R11 (bit-identical outputs). 3 barriers/rule (was 4).
__global__ __launch_bounds__(512) void k3_cons(
    const bf16_t* __restrict__ datab,
    const bf16_t* __restrict__ Wc1p, const bf16_t* __restrict__ Wc2p, const bf16_t* __restrict__ Wc3p,
    const float* __restrict__ bc1, const float* __restrict__ bc2, const float* __restrict__ bc3,
    float* __restrict__ c3buf)
{
  __shared__ __attribute__((aligned(16))) char smem[73728];
  char* d_lds  = smem;           // [64][256] bf16 swz8 (persistent across both rules)
  char* c1_lds = smem + 32768;   // [64 b][256 g1] bf16 swz8
  char* c2_lds = smem + 65536;   // [64 b][64 g2] bf16 swz8

  // XCD swizzle over 4096 blocks: xcd owns rule-pairs {2*xcd, 2*xcd+1} (4 rules, same as R11)
  const int bid = blockIdx.x;
  const int xcd = bid & 7;
  const int kk  = bid >> 3;            // 0..511
  const int rp  = xcd * 2 + (kk >> 8); // rule pair 0..15
  const int b0  = (kk & 255) << 6;

  const int tid = threadIdx.x;
  const int lane = tid & 63;
  const int w   = tid >> 6;

  { // stage data tile once
    const int row = tid >> 3;
    const int e0  = (tid & 7) << 5;
    const bf16_t* sp = datab + (long)(b0 + row) * FN + e0;
    char* drow = d_lds + row * 512;
    const int sw = (row & 7) << 4;
    #pragma unroll
    for (int i = 0; i < 4; ++i) {
      bf16x8 v = *(const bf16x8*)(sp + i * 8);
      *(bf16x8*)(drow + (((e0 + i * 8) * 2) ^ sw)) = v;
    }
  }
  __syncthreads();

  for (int rr = 0; rr < 2; ++rr) {
    const int r = rp * 2 + rr;

    // GEMM1: c1T[g1=256][b=64]. wave w -> m-tiles {2w,2w+1}, all 4 n-tiles (R11 layout).
    const bf16_t* W1 = Wc1p + (long)r * G1N * FN;
    f32x4 acc[2][4] = {};
    #pragma unroll
    for (int ks = 0; ks < 8; ++ks) {
      bf16x8 a[2], bb[4];
      #pragma unroll
      for (int i = 0; i < 2; ++i)
        a[i] = *(const bf16x8*)(W1 + (((ks * 16 + w * 2 + i) * 64 + lane)) * 8);
      #pragma unroll
      for (int j = 0; j < 4; ++j)
        bb[j] = lfrag(d_lds, 512, j * 16, ks * 32, lane);
      #pragma unroll
      for (int i = 0; i < 2; ++i)
        #pragma unroll
        for (int j = 0; j < 4; ++j)
          acc[i][j] = mfma16(a[i], bb[j], acc[i][j]);
    }
    // c1T epilogue (c1 region is free: rule rr-1's GEMM2 readers passed the post-GEMM3 barrier)
    #pragma unroll
    for (int i = 0; i < 2; ++i) {
      const int g1b = (w * 2 + i) * 16 + ((lane >> 4) << 2);
      f32x4 bias = *(const f32x4*)(bc1 + r * G1N + g1b);
      #pragma unroll
      for (int j = 0; j < 4; ++j) {
        const int b = j * 16 + (lane & 15);
        bf16x4 o;
        #pragma unroll
        for (int q = 0; q < 4; ++q)
          o[q] = (bf16_t)elu_f(acc[i][j][q] + bias[q]);
        *(bf16x4*)(c1_lds + b * 512 + ((g1b * 2) ^ ((b & 7) << 4))) = o;
      }
    }
    __syncthreads();   // c1T ready

    // GEMM2: c2T[g2=64][b=64]. 4m x 4n tiles; wave: m = w>>1, n-tiles {2(w&1), 2(w&1)+1} (R11).
    {
      const int m2 = w >> 1;
      const int n2 = w & 1;
      const bf16_t* W2 = Wc2p + (long)r * G2N * G1N;
      f32x4 acc2[2] = {};
      #pragma unroll
      for (int ks = 0; ks < 8; ++ks) {
        bf16x8 a = *(const bf16x8*)(W2 + (((ks * 4 + m2) * 64 + lane)) * 8);
        #pragma unroll
        for (int j = 0; j < 2; ++j) {
          bf16x8 bb = lfrag(c1_lds, 512, (n2 * 2 + j) * 16, ks * 32, lane);
          acc2[j] = mfma16(a, bb, acc2[j]);
        }
      }
      const int g2b = m2 * 16 + ((lane >> 4) << 2);
      f32x4 bias = *(const f32x4*)(bc2 + r * G2N + g2b);
      #pragma unroll
      for (int j = 0; j < 2; ++j) {
        const int b = (n2 * 2 + j) * 16 + (lane & 15);
        bf16x4 o;
        #pragma unroll
        for (int q = 0; q < 4; ++q)
          o[q] = (bf16_t)elu_f(acc2[j][q] + bias[q]);
        *(bf16x4*)(c2_lds + b * 128 + ((g2b * 2) ^ ((b & 7) << 4))) = o;
      }
    }
    __syncthreads();   // c2T ready

    // GEMM3: c3T[c=16][b=64]. 4 n-tiles; waves 0-3. K=64.
    if (w < 4) {
      const bf16_t* W3 = Wc3p + (long)r * CN * G2N;
      f32x4 acc3 = {};
      #pragma unroll
      for (int ks = 0; ks < 2; ++ks) {
        bf16x8 a = *(const bf16x8*)(W3 + (((long)ks * 64 + lane)) * 8);
        bf16x8 bb = lfrag(c2_lds, 128, w * 16, ks * 32, lane);
        acc3 = mfma16(a, bb, acc3);
      }
      const int c0 = ((lane >> 4) << 2);
      const int b  = w * 16 + (lane & 15);
      f32x4 bias = *(const f32x4*)(bc3 + r * CN + c0);
      f32x4 o;
      #pragma unroll
      for (int q = 0; q < 4; ++q) o[q] = fmaxf(acc3[q] + bias[q], 0.f);
      *(f32x4*)(c3buf + ((long)r * BN + b0 + b) * CN + c0) = o;
    }
    __syncthreads();   // c2T (and c1T) free for next rule
  }
}

// k4: softmax over rules (from fsini) + weighted combine + fire output. Replaces k2+k4.
__global__ __launch_bounds__(256) void k4_out(const float* __restrict__ fsini,
                                              const float* __restrict__ c3buf,
                                              float* __restrict__ out,
                                              float* __restrict__ fire_g)
{
  int t = blockIdx.x * 256 + threadIdx.x;   // over B*C/4
  int b = t >> 2, c4 = (t & 3) << 2;
  float v[RN];
  const float4* p = (const float4*)(fsini + (long)b * RN);
  #pragma unroll
  for (int i = 0; i < RN / 4; ++i) {
    float4 x = p[i];
    v[4 * i] = x.x; v[4 * i + 1] = x.y; v[4 * i + 2] = x.z; v[4 * i + 3] = x.w;
  }
  float m = v[0];
  #pragma unroll
  for (int i = 1; i < RN; ++i) m = fmaxf(m, v[i]);
  float s = 0.f;
  #pragma unroll
  for (int i = 0; i < RN; ++i) { v[i] = expf(v[i] - m); s += v[i]; }
  float inv = 1.f / s;
  #pragma unroll
  for (int i = 0; i < RN; ++i) v[i] *= inv;

  f32x4 acc = {};
  #pragma unroll
  for (int rrr = 0; rrr < RN; ++rrr) {
    f32x4 c = *(const f32x4*)(c3buf + ((long)rrr * BN + b) * CN + c4);
    acc += v[rrr] * c;
  }
  *(f32x4*)(out + (long)b * CN + c4) = acc;

  if (c4 == 0) {  // one thread per batch row writes fire
    float4* o = (float4*)(fire_g + (long)b * RN);
    #pragma unroll
    for (int i = 0; i < RN / 4; ++i) {
      float4 x; x.x = v[4 * i]; x.y = v[4 * i + 1]; x.z = v[4 * i + 2]; x.w = v[4 * i + 3];
      o[i] = x;
    }
  }
}

extern "C" void kernel_launch(void* const* d_in, const int* in_sizes, int n_in,
                              void* d_out, int out_size, void* d_ws, size_t ws_size,
                              hipStream_t stream) {
  const float* data = (const float*)d_in[0];
  const float* proto = (const float*)d_in[1];
  const float* var  = (const float*)d_in[2];
  const float* Wf1  = (const float*)d_in[3];
  const float* bf1  = (const float*)d_in[4];
  const float* Wf2  = (const float*)d_in[5];
  const float* bf2  = (const float*)d_in[6];
  const float* Wf3  = (const float*)d_in[7];
  const float* bf3  = (const float*)d_in[8];
  const float* Wc1  = (const float*)d_in[9];
  const float* bc1  = (const float*)d_in[10];
  const float* Wc2  = (const float*)d_in[11];
  const float* bc2  = (const float*)d_in[12];
  const float* Wc3  = (const float*)d_in[13];
  const float* bc3  = (const float*)d_in[14];

  char* ws = (char*)d_ws;
  bf16_t* datab = (bf16_t*)(ws + OFF_DATA);
  bf16_t* Wf1p  = (bf16_t*)(ws + OFF_WF1);
  bf16_t* Wf2p  = (bf16_t*)(ws + OFF_WF2);
  bf16_t* Wc1p  = (bf16_t*)(ws + OFF_WC1);
  bf16_t* Wc2p  = (bf16_t*)(ws + OFF_WC2);
  bf16_t* Wc3p  = (bf16_t*)(ws + OFF_WC3);
  float*  fsini = (float*)(ws + OFF_FSINI);
  float*  c3buf = (float*)(ws + OFF_C3);

  float* out  = (float*)d_out;               // [B][C]
  float* fire = out + (long)BN * CN;         // [B][R]

  k0_pack<<<G_TOTAL / 256, 256, 0, stream>>>(data, Wf1, Wf2, Wc1, Wc2, Wc3, ws);
  k3_cons<<<16 * (BN / 64) / 2 * 2, 512, 0, stream>>>(datab, Wc1p, Wc2p, Wc3p,
                                                      bc1, bc2, bc3, c3buf);
  k1_fs<<<RN * (BN / 64), 512, 0, stream>>>(data, proto, var, bf1, bf2, Wf3, bf3,
                                            Wf1p, Wf2p, fsini);
  k4_out<<<(BN * CN / 4) / 256, 256, 0, stream>>>(fsini, c3buf, out, fire);
}

// Round 19
// 255.632 us; speedup vs baseline: 1.5769x; 1.0021x over previous
//
#include <hip/hip_runtime.h>
#include <hip/hip_bf16.h>

// Problem dims
#define BN 16384
#define FN 256
#define RN 32
#define CN 16
#define H1N 128
#define H2N 32
#define G1N 256
#define G2N 64

typedef __bf16 bf16_t;
typedef __bf16 bf16x8 __attribute__((ext_vector_type(8)));
typedef __bf16 bf16x4 __attribute__((ext_vector_type(4)));
typedef float f32x4 __attribute__((ext_vector_type(4)));

// ---- workspace byte offsets ----
#define OFF_DATA   0UL
#define OFF_WF1    8388608UL
#define OFF_WF2    8454144UL
#define OFF_WC1    8462336UL
#define OFF_WC2    12656640UL
#define OFF_WC3    13705216UL
#define OFF_FSINI  13770752UL
#define OFF_C3     15867904UL

__device__ __forceinline__ f32x4 mfma16(bf16x8 a, bf16x8 b, f32x4 c) {
  return __builtin_amdgcn_mfma_f32_16x16x32_bf16(a, b, c, 0, 0, 0);
}

__device__ __forceinline__ float elu_f(float v) {
  float e = __builtin_amdgcn_exp2f(v * 1.44269504f) - 1.0f;
  return v > 0.f ? v : e;
}

// B-frag from ((row&7)<<4)-XOR-swizzled LDS tile (row stride strideB bytes).
__device__ __forceinline__ bf16x8 lfrag(const char* base, int strideB, int n0, int k0, int lane) {
  int row = n0 + (lane & 15);
  int off = (k0 * 2 + ((lane >> 4) << 4)) ^ ((row & 7) << 4);
  return *(const bf16x8*)(base + row * strideB + off);
}

// Pack W[(r,)n,k] fp32 -> 16x16x32 fragment order bf16.
__device__ __forceinline__ void pack_frag8(const float* __restrict__ src, bf16_t* __restrict__ dst,
                                           int NT, int KS, int g) {
  int per = NT * KS * 64;
  int r = g / per;
  int local = g - r * per;
  int lane = local & 63;
  int fr = local >> 6;
  int ks = fr / NT;
  int nt = fr - ks * NT;
  int N = NT * 16, K = KS * 32;
  int n = nt * 16 + (lane & 15);
  int k = ks * 32 + ((lane >> 4) << 3);
  const float* s = src + (long)r * N * K + (long)n * K + k;
  float4 a = *(const float4*)s;
  float4 b = *(const float4*)(s + 4);
  bf16x8 o;
  o[0] = (bf16_t)a.x; o[1] = (bf16_t)a.y; o[2] = (bf16_t)a.z; o[3] = (bf16_t)a.w;
  o[4] = (bf16_t)b.x; o[5] = (bf16_t)b.y; o[6] = (bf16_t)b.z; o[7] = (bf16_t)b.w;
  *(bf16x8*)(dst + (long)g * 8) = o;
}

#define G_DATA 524288
#define G_WC1  262144
#define G_WC2  65536
#define G_WF1  4096
#define G_WC3  4096
#define G_WF2  512
#define G_TOTAL (G_DATA + G_WC1 + G_WC2 + G_WF1 + G_WC3 + G_WF2)

__global__ __launch_bounds__(256) void k0_pack(
    const float* __restrict__ data, const float* __restrict__ Wf1, const float* __restrict__ Wf2,
    const float* __restrict__ Wc1, const float* __restrict__ Wc2, const float* __restrict__ Wc3,
    char* __restrict__ ws)
{
  int g = blockIdx.x * 256 + threadIdx.x;
  if (g < G_DATA) {
    const float* s = data + (long)g * 8;
    float4 a = *(const float4*)s, b = *(const float4*)(s + 4);
    bf16x8 o;
    o[0] = (bf16_t)a.x; o[1] = (bf16_t)a.y; o[2] = (bf16_t)a.z; o[3] = (bf16_t)a.w;
    o[4] = (bf16_t)b.x; o[5] = (bf16_t)b.y; o[6] = (bf16_t)b.z; o[7] = (bf16_t)b.w;
    *(bf16x8*)((bf16_t*)(ws + OFF_DATA) + (long)g * 8) = o;
    return;
  }
  g -= G_DATA;
  if (g < G_WC1) { pack_frag8(Wc1, (bf16_t*)(ws + OFF_WC1), 16, 8, g); return; }
  g -= G_WC1;
  if (g < G_WC2) { pack_frag8(Wc2, (bf16_t*)(ws + OFF_WC2), 4, 8, g); return; }
  g -= G_WC2;
  if (g < G_WF1) { pack_frag8(Wf1, (bf16_t*)(ws + OFF_WF1), 8, 8, g); return; }
  g -= G_WF1;
  if (g < G_WC3) { pack_frag8(Wc3, (bf16_t*)(ws + OFF_WC3), 1, 2, g); return; }
  g -= G_WC3;
  if (g < G_WF2) { pack_frag8(Wf2, (bf16_t*)(ws + OFF_WF2), 2, 4, g); return; }
}

// ---------------- K1: FS chain, per (rule, 128-row tile) ----------------
// 2x work per barrier vs 64-row version (K3's verified win mechanism).
// LDS: mem [128][256] bf16 swz8 (64KB, h1T [128][128] overlays lower 32KB after GEMM1)
//      + h2t [32][128] bf16 (8KB) + proto/ivar (2KB) = 74KB -> 2 blocks/CU.
__global__ __launch_bounds__(512) void k1_fs(
    const float* __restrict__ data, const float* __restrict__ proto, const float* __restrict__ var,
    const float* __restrict__ bf1g, const float* __restrict__ bf2g,
    const float* __restrict__ Wf3g, const float* __restrict__ bf3g,
    const bf16_t* __restrict__ Wf1p, const bf16_t* __restrict__ Wf2p,
    float* __restrict__ fsini)
{
  __shared__ __attribute__((aligned(16))) char smem[75776];
  char* fs_lds   = smem;                      // mem [128][256] bf16 swz8; h1T overlays [0,32768)
  bf16_t* h2t    = (bf16_t*)(smem + 65536);   // [32][128]
  float* proto_s = (float*)(smem + 73728);
  float* ivar_s  = (float*)(smem + 74752);

  const int bid = blockIdx.x;
  const int r   = bid >> 7;                   // 0..31
  const int b0  = (bid & 127) << 7;           // 128-row tile
  const int tid = threadIdx.x;
  const int lane = tid & 63;
  const int w   = tid >> 6;

  if (tid < FN) {
    proto_s[tid] = proto[r * FN + tid];
    float v = var[r * FN + tid];
    v = fminf(fmaxf(v, 1e-4f), 0.1f);
    ivar_s[tid] = 1.4426950408889634f * 0.5f / (v * v);
  }
  __syncthreads();

  { // membership: 4 threads/row, 64 feats each
    const int row = tid >> 2;
    const int f0  = (tid & 3) << 6;
    const float* dp = data + (long)(b0 + row) * FN + f0;
    char* mrow = fs_lds + row * 512;
    const int sw = (row & 7) << 4;
    #pragma unroll
    for (int i = 0; i < 8; ++i) {
      const int f = f0 + i * 8;
      float4 x0 = *(const float4*)(dp + i * 8);
      float4 x1 = *(const float4*)(dp + i * 8 + 4);
      bf16x8 m; float d;
      d = x0.x - proto_s[f + 0]; m[0] = (bf16_t)__builtin_amdgcn_exp2f(-d * d * ivar_s[f + 0]);
      d = x0.y - proto_s[f + 1]; m[1] = (bf16_t)__builtin_amdgcn_exp2f(-d * d * ivar_s[f + 1]);
      d = x0.z - proto_s[f + 2]; m[2] = (bf16_t)__builtin_amdgcn_exp2f(-d * d * ivar_s[f + 2]);
      d = x0.w - proto_s[f + 3]; m[3] = (bf16_t)__builtin_amdgcn_exp2f(-d * d * ivar_s[f + 3]);
      d = x1.x - proto_s[f + 4]; m[4] = (bf16_t)__builtin_amdgcn_exp2f(-d * d * ivar_s[f + 4]);
      d = x1.y - proto_s[f + 5]; m[5] = (bf16_t)__builtin_amdgcn_exp2f(-d * d * ivar_s[f + 5]);
      d = x1.z - proto_s[f + 6]; m[6] = (bf16_t)__builtin_amdgcn_exp2f(-d * d * ivar_s[f + 6]);
      d = x1.w - proto_s[f + 7]; m[7] = (bf16_t)__builtin_amdgcn_exp2f(-d * d * ivar_s[f + 7]);
      *(bf16x8*)(mrow + ((f * 2) ^ sw)) = m;
    }
  }
  __syncthreads();

  // GEMM1: h1T[h=128][b=128] = Wf1 @ memT. 8m x 8n tiles; wave w -> m-tile w, all 8 n.
  f32x4 acc[8] = {};
  #pragma unroll
  for (int ks = 0; ks < 8; ++ks) {
    bf16x8 a = *(const bf16x8*)(Wf1p + (((ks * 8 + w) * 64 + lane)) * 8);
    #pragma unroll
    for (int j = 0; j < 8; ++j) {
      bf16x8 bb = lfrag(fs_lds, 512, j * 16, ks * 32, lane);
      acc[j] = mfma16(a, bb, acc[j]);
    }
  }
  __syncthreads();   // mem dead -> overlay h1T [128 b][128 h] in [0,32768)

  {
    const int hb = w * 16 + ((lane >> 4) << 2);
    f32x4 bias = *(const f32x4*)(bf1g + hb);
    #pragma unroll
    for (int j = 0; j < 8; ++j) {
      const int b = j * 16 + (lane & 15);
      bf16x4 o;
      #pragma unroll
      for (int q = 0; q < 4; ++q)
        o[q] = (bf16_t)fmaxf(acc[j][q] + bias[q], 0.f);
      *(bf16x4*)(fs_lds + b * 256 + ((hb * 2) ^ ((b & 7) << 4))) = o;
    }
  }
  __syncthreads();

  // GEMM2: h2T[p=32][b=128] = Wf2 @ h1T. 2m x 8n tiles; wave: m = w>>2, n-tiles (w&3)*2+{0,1}.
  {
    const int m = w >> 2;
    f32x4 acc2[2] = {};
    #pragma unroll
    for (int ks = 0; ks < 4; ++ks) {
      bf16x8 a = *(const bf16x8*)(Wf2p + (((ks * 2 + m) * 64 + lane)) * 8);
      #pragma unroll
      for (int j = 0; j < 2; ++j) {
        bf16x8 bb = lfrag(fs_lds, 256, ((w & 3) * 2 + j) * 16, ks * 32, lane);
        acc2[j] = mfma16(a, bb, acc2[j]);
      }
    }
    const int p0 = m * 16 + ((lane >> 4) << 2);
    f32x4 bias = *(const f32x4*)(bf2g + p0);
    #pragma unroll
    for (int j = 0; j < 2; ++j) {
      const int b = ((w & 3) * 2 + j) * 16 + (lane & 15);
      #pragma unroll
      for (int q = 0; q < 4; ++q)
        h2t[(p0 + q) * 128 + b] = (bf16_t)fmaxf(acc2[j][q] + bias[q], 0.f);
    }
  }
  __syncthreads();

  if (tid < 128) {
    float s = bf3g[0];
    #pragma unroll
    for (int p = 0; p < H2N; ++p) s += (float)h2t[p * 128 + tid] * Wf3g[p];
    fsini[(long)(b0 + tid) * RN + r] = fmaxf(s, 0.f);
  }
}

// ---------------- K3: consequent chain, 2 rules per block, data staged once (R18, verified) ----------------
__global__ __launch_bounds__(512) void k3_cons(
    const bf16_t* __restrict__ datab,
    const bf16_t* __restrict__ Wc1p, const bf16_t* __restrict__ Wc2p, const bf16_t* __restrict__ Wc3p,
    const float* __restrict__ bc1, const float* __restrict__ bc2, const float* __restrict__ bc3,
    float* __restrict__ c3buf)
{
  __shared__ __attribute__((aligned(16))) char smem[73728];
  char* d_lds  = smem;           // [64][256] bf16 swz8 (persistent across both rules)
  char* c1_lds = smem + 32768;   // [64 b][256 g1] bf16 swz8
  char* c2_lds = smem + 65536;   // [64 b][64 g2] bf16 swz8

  const int bid = blockIdx.x;
  const int xcd = bid & 7;
  const int kk  = bid >> 3;            // 0..511
  const int rp  = xcd * 2 + (kk >> 8); // rule pair 0..15
  const int b0  = (kk & 255) << 6;

  const int tid = threadIdx.x;
  const int lane = tid & 63;
  const int w   = tid >> 6;

  { // stage data tile once
    const int row = tid >> 3;
    const int e0  = (tid & 7) << 5;
    const bf16_t* sp = datab + (long)(b0 + row) * FN + e0;
    char* drow = d_lds + row * 512;
    const int sw = (row & 7) << 4;
    #pragma unroll
    for (int i = 0; i < 4; ++i) {
      bf16x8 v = *(const bf16x8*)(sp + i * 8);
      *(bf16x8*)(drow + (((e0 + i * 8) * 2) ^ sw)) = v;
    }
  }
  __syncthreads();

  for (int rr = 0; rr < 2; ++rr) {
    const int r = rp * 2 + rr;

    // GEMM1: c1T[g1=256][b=64]. wave w -> m-tiles {2w,2w+1}, all 4 n-tiles.
    const bf16_t* W1 = Wc1p + (long)r * G1N * FN;
    f32x4 acc[2][4] = {};
    #pragma unroll
    for (int ks = 0; ks < 8; ++ks) {
      bf16x8 a[2], bb[4];
      #pragma unroll
      for (int i = 0; i < 2; ++i)
        a[i] = *(const bf16x8*)(W1 + (((ks * 16 + w * 2 + i) * 64 + lane)) * 8);
      #pragma unroll
      for (int j = 0; j < 4; ++j)
        bb[j] = lfrag(d_lds, 512, j * 16, ks * 32, lane);
      #pragma unroll
      for (int i = 0; i < 2; ++i)
        #pragma unroll
        for (int j = 0; j < 4; ++j)
          acc[i][j] = mfma16(a[i], bb[j], acc[i][j]);
    }
    #pragma unroll
    for (int i = 0; i < 2; ++i) {
      const int g1b = (w * 2 + i) * 16 + ((lane >> 4) << 2);
      f32x4 bias = *(const f32x4*)(bc1 + r * G1N + g1b);
      #pragma unroll
      for (int j = 0; j < 4; ++j) {
        const int b = j * 16 + (lane & 15);
        bf16x4 o;
        #pragma unroll
        for (int q = 0; q < 4; ++q)
          o[q] = (bf16_t)elu_f(acc[i][j][q] + bias[q]);
        *(bf16x4*)(c1_lds + b * 512 + ((g1b * 2) ^ ((b & 7) << 4))) = o;
      }
    }
    __syncthreads();   // c1T ready

    // GEMM2: c2T[g2=64][b=64]. wave: m = w>>1, n-tiles {2(w&1), 2(w&1)+1}.
    {
      const int m2 = w >> 1;
      const int n2 = w & 1;
      const bf16_t* W2 = Wc2p + (long)r * G2N * G1N;
      f32x4 acc2[2] = {};
      #pragma unroll
      for (int ks = 0; ks < 8; ++ks) {
        bf16x8 a = *(const bf16x8*)(W2 + (((ks * 4 + m2) * 64 + lane)) * 8);
        #pragma unroll
        for (int j = 0; j < 2; ++j) {
          bf16x8 bb = lfrag(c1_lds, 512, (n2 * 2 + j) * 16, ks * 32, lane);
          acc2[j] = mfma16(a, bb, acc2[j]);
        }
      }
      const int g2b = m2 * 16 + ((lane >> 4) << 2);
      f32x4 bias = *(const f32x4*)(bc2 + r * G2N + g2b);
      #pragma unroll
      for (int j = 0; j < 2; ++j) {
        const int b = (n2 * 2 + j) * 16 + (lane & 15);
        bf16x4 o;
        #pragma unroll
        for (int q = 0; q < 4; ++q)
          o[q] = (bf16_t)elu_f(acc2[j][q] + bias[q]);
        *(bf16x4*)(c2_lds + b * 128 + ((g2b * 2) ^ ((b & 7) << 4))) = o;
      }
    }
    __syncthreads();   // c2T ready

    // GEMM3: c3T[c=16][b=64]. 4 n-tiles; waves 0-3. K=64.
    if (w < 4) {
      const bf16_t* W3 = Wc3p + (long)r * CN * G2N;
      f32x4 acc3 = {};
      #pragma unroll
      for (int ks = 0; ks < 2; ++ks) {
        bf16x8 a = *(const bf16x8*)(W3 + (((long)ks * 64 + lane)) * 8);
        bf16x8 bb = lfrag(c2_lds, 128, w * 16, ks * 32, lane);
        acc3 = mfma16(a, bb, acc3);
      }
      const int c0 = ((lane >> 4) << 2);
      const int b  = w * 16 + (lane & 15);
      f32x4 bias = *(const f32x4*)(bc3 + r * CN + c0);
      f32x4 o;
      #pragma unroll
      for (int q = 0; q < 4; ++q) o[q] = fmaxf(acc3[q] + bias[q], 0.f);
      *(f32x4*)(c3buf + ((long)r * BN + b0 + b) * CN + c0) = o;
    }
    __syncthreads();   // c1T/c2T free for next rule
  }
}

// k4: softmax over rules + weighted combine + fire output.
__global__ __launch_bounds__(256) void k4_out(const float* __restrict__ fsini,
                                              const float* __restrict__ c3buf,
                                              float* __restrict__ out,
                                              float* __restrict__ fire_g)
{
  int t = blockIdx.x * 256 + threadIdx.x;   // over B*C/4
  int b = t >> 2, c4 = (t & 3) << 2;
  float v[RN];
  const float4* p = (const float4*)(fsini + (long)b * RN);
  #pragma unroll
  for (int i = 0; i < RN / 4; ++i) {
    float4 x = p[i];
    v[4 * i] = x.x; v[4 * i + 1] = x.y; v[4 * i + 2] = x.z; v[4 * i + 3] = x.w;
  }
  float m = v[0];
  #pragma unroll
  for (int i = 1; i < RN; ++i) m = fmaxf(m, v[i]);
  float s = 0.f;
  #pragma unroll
  for (int i = 0; i < RN; ++i) { v[i] = expf(v[i] - m); s += v[i]; }
  float inv = 1.f / s;
  #pragma unroll
  for (int i = 0; i < RN; ++i) v[i] *= inv;

  f32x4 acc = {};
  #pragma unroll
  for (int rrr = 0; rrr < RN; ++rrr) {
    f32x4 c = *(const f32x4*)(c3buf + ((long)rrr * BN + b) * CN + c4);
    acc += v[rrr] * c;
  }
  *(f32x4*)(out + (long)b * CN + c4) = acc;

  if (c4 == 0) {
    float4* o = (float4*)(fire_g + (long)b * RN);
    #pragma unroll
    for (int i = 0; i < RN / 4; ++i) {
      float4 x; x.x = v[4 * i]; x.y = v[4 * i + 1]; x.z = v[4 * i + 2]; x.w = v[4 * i + 3];
      o[i] = x;
    }
  }
}

extern "C" void kernel_launch(void* const* d_in, const int* in_sizes, int n_in,
                              void* d_out, int out_size, void* d_ws, size_t ws_size,
                              hipStream_t stream) {
  const float* data = (const float*)d_in[0];
  const float* proto = (const float*)d_in[1];
  const float* var  = (const float*)d_in[2];
  const float* Wf1  = (const float*)d_in[3];
  const float* bf1  = (const float*)d_in[4];
  const float* Wf2  = (const float*)d_in[5];
  const float* bf2  = (const float*)d_in[6];
  const float* Wf3  = (const float*)d_in[7];
  const float* bf3  = (const float*)d_in[8];
  const float* Wc1  = (const float*)d_in[9];
  const float* bc1  = (const float*)d_in[10];
  const float* Wc2  = (const float*)d_in[11];
  const float* bc2  = (const float*)d_in[12];
  const float* Wc3  = (const float*)d_in[13];
  const float* bc3  = (const float*)d_in[14];

  char* ws = (char*)d_ws;
  bf16_t* datab = (bf16_t*)(ws + OFF_DATA);
  bf16_t* Wf1p  = (bf16_t*)(ws + OFF_WF1);
  bf16_t* Wf2p  = (bf16_t*)(ws + OFF_WF2);
  bf16_t* Wc1p  = (bf16_t*)(ws + OFF_WC1);
  bf16_t* Wc2p  = (bf16_t*)(ws + OFF_WC2);
  bf16_t* Wc3p  = (bf16_t*)(ws + OFF_WC3);
  float*  fsini = (float*)(ws + OFF_FSINI);
  float*  c3buf = (float*)(ws + OFF_C3);

  float* out  = (float*)d_out;               // [B][C]
  float* fire = out + (long)BN * CN;         // [B][R]

  k0_pack<<<G_TOTAL / 256, 256, 0, stream>>>(data, Wf1, Wf2, Wc1, Wc2, Wc3, ws);
  k3_cons<<<16 * (BN / 64) / 2 * 2, 512, 0, stream>>>(datab, Wc1p, Wc2p, Wc3p,
                                                      bc1, bc2, bc3, c3buf);
  k1_fs<<<RN * (BN / 128), 512, 0, stream>>>(data, proto, var, bf1, bf2, Wf3, bf3,
                                             Wf1p, Wf2p, fsini);
  k4_out<<<(BN * CN / 4) / 256, 256, 0, stream>>>(fsini, c3buf, out, fire);
}

// Round 20
// 248.660 us; speedup vs baseline: 1.6211x; 1.0280x over previous
//
#include <hip/hip_runtime.h>
#include <hip/hip_bf16.h>

// Problem dims
#define BN 16384
#define FN 256
#define RN 32
#define CN 16
#define H1N 128
#define H2N 32
#define G1N 256
#define G2N 64

typedef __bf16 bf16_t;
typedef __bf16 bf16x8 __attribute__((ext_vector_type(8)));
typedef __bf16 bf16x4 __attribute__((ext_vector_type(4)));
typedef float f32x4 __attribute__((ext_vector_type(4)));

// ---- workspace byte offsets ----
#define OFF_DATA   0UL
#define OFF_WF1    8388608UL
#define OFF_WF2    8454144UL
#define OFF_WC1    8462336UL
#define OFF_WC2    12656640UL
#define OFF_WC3    13705216UL
#define OFF_FSINI  13770752UL
#define OFF_C3     15867904UL

__device__ __forceinline__ f32x4 mfma16(bf16x8 a, bf16x8 b, f32x4 c) {
  return __builtin_amdgcn_mfma_f32_16x16x32_bf16(a, b, c, 0, 0, 0);
}

__device__ __forceinline__ float elu_f(float v) {
  float e = __builtin_amdgcn_exp2f(v * 1.44269504f) - 1.0f;
  return v > 0.f ? v : e;
}

// B-frag, 3-bit XOR swizzle ((row&7)<<4) — for 128B-row tiles only (c2T).
__device__ __forceinline__ bf16x8 lfrag(const char* base, int strideB, int n0, int k0, int lane) {
  int row = n0 + (lane & 15);
  int off = (k0 * 2 + ((lane >> 4) << 4)) ^ ((row & 7) << 4);
  return *(const bf16x8*)(base + row * strideB + off);
}

// B-frag, 4-bit XOR swizzle ((row&15)<<4) — for >=256B-row tiles.
// 16 fragment rows -> 16 distinct 16B slots -> only the free 2-way aliasing.
__device__ __forceinline__ bf16x8 lfrag16(const char* base, int strideB, int n0, int k0, int lane) {
  int row = n0 + (lane & 15);
  int off = (k0 * 2 + ((lane >> 4) << 4)) ^ ((row & 15) << 4);
  return *(const bf16x8*)(base + row * strideB + off);
}

// Pack W[(r,)n,k] fp32 -> 16x16x32 fragment order bf16.
__device__ __forceinline__ void pack_frag8(const float* __restrict__ src, bf16_t* __restrict__ dst,
                                           int NT, int KS, int g) {
  int per = NT * KS * 64;
  int r = g / per;
  int local = g - r * per;
  int lane = local & 63;
  int fr = local >> 6;
  int ks = fr / NT;
  int nt = fr - ks * NT;
  int N = NT * 16, K = KS * 32;
  int n = nt * 16 + (lane & 15);
  int k = ks * 32 + ((lane >> 4) << 3);
  const float* s = src + (long)r * N * K + (long)n * K + k;
  float4 a = *(const float4*)s;
  float4 b = *(const float4*)(s + 4);
  bf16x8 o;
  o[0] = (bf16_t)a.x; o[1] = (bf16_t)a.y; o[2] = (bf16_t)a.z; o[3] = (bf16_t)a.w;
  o[4] = (bf16_t)b.x; o[5] = (bf16_t)b.y; o[6] = (bf16_t)b.z; o[7] = (bf16_t)b.w;
  *(bf16x8*)(dst + (long)g * 8) = o;
}

#define G_DATA 524288
#define G_WC1  262144
#define G_WC2  65536
#define G_WF1  4096
#define G_WC3  4096
#define G_WF2  512
#define G_TOTAL (G_DATA + G_WC1 + G_WC2 + G_WF1 + G_WC3 + G_WF2)

__global__ __launch_bounds__(256) void k0_pack(
    const float* __restrict__ data, const float* __restrict__ Wf1, const float* __restrict__ Wf2,
    const float* __restrict__ Wc1, const float* __restrict__ Wc2, const float* __restrict__ Wc3,
    char* __restrict__ ws)
{
  int g = blockIdx.x * 256 + threadIdx.x;
  if (g < G_DATA) {
    const float* s = data + (long)g * 8;
    float4 a = *(const float4*)s, b = *(const float4*)(s + 4);
    bf16x8 o;
    o[0] = (bf16_t)a.x; o[1] = (bf16_t)a.y; o[2] = (bf16_t)a.z; o[3] = (bf16_t)a.w;
    o[4] = (bf16_t)b.x; o[5] = (bf16_t)b.y; o[6] = (bf16_t)b.z; o[7] = (bf16_t)b.w;
    *(bf16x8*)((bf16_t*)(ws + OFF_DATA) + (long)g * 8) = o;
    return;
  }
  g -= G_DATA;
  if (g < G_WC1) { pack_frag8(Wc1, (bf16_t*)(ws + OFF_WC1), 16, 8, g); return; }
  g -= G_WC1;
  if (g < G_WC2) { pack_frag8(Wc2, (bf16_t*)(ws + OFF_WC2), 4, 8, g); return; }
  g -= G_WC2;
  if (g < G_WF1) { pack_frag8(Wf1, (bf16_t*)(ws + OFF_WF1), 8, 8, g); return; }
  g -= G_WF1;
  if (g < G_WC3) { pack_frag8(Wc3, (bf16_t*)(ws + OFF_WC3), 1, 2, g); return; }
  g -= G_WC3;
  if (g < G_WF2) { pack_frag8(Wf2, (bf16_t*)(ws + OFF_WF2), 2, 4, g); return; }
}

// ---------------- K1: FS chain, per (rule, 128-row tile). 4-bit swizzle. ----------------
__global__ __launch_bounds__(512) void k1_fs(
    const float* __restrict__ data, const float* __restrict__ proto, const float* __restrict__ var,
    const float* __restrict__ bf1g, const float* __restrict__ bf2g,
    const float* __restrict__ Wf3g, const float* __restrict__ bf3g,
    const bf16_t* __restrict__ Wf1p, const bf16_t* __restrict__ Wf2p,
    float* __restrict__ fsini)
{
  __shared__ __attribute__((aligned(16))) char smem[75776];
  char* fs_lds   = smem;                      // mem [128][256] bf16 swz16; h1T [128][128] swz16 overlays
  bf16_t* h2t    = (bf16_t*)(smem + 65536);   // [32][128]
  float* proto_s = (float*)(smem + 73728);
  float* ivar_s  = (float*)(smem + 74752);

  const int bid = blockIdx.x;
  const int r   = bid >> 7;
  const int b0  = (bid & 127) << 7;
  const int tid = threadIdx.x;
  const int lane = tid & 63;
  const int w   = tid >> 6;

  if (tid < FN) {
    proto_s[tid] = proto[r * FN + tid];
    float v = var[r * FN + tid];
    v = fminf(fmaxf(v, 1e-4f), 0.1f);
    ivar_s[tid] = 1.4426950408889634f * 0.5f / (v * v);
  }
  __syncthreads();

  { // membership: 4 threads/row, 64 feats each; swz16 write
    const int row = tid >> 2;
    const int f0  = (tid & 3) << 6;
    const float* dp = data + (long)(b0 + row) * FN + f0;
    char* mrow = fs_lds + row * 512;
    const int sw = (row & 15) << 4;
    #pragma unroll
    for (int i = 0; i < 8; ++i) {
      const int f = f0 + i * 8;
      float4 x0 = *(const float4*)(dp + i * 8);
      float4 x1 = *(const float4*)(dp + i * 8 + 4);
      bf16x8 m; float d;
      d = x0.x - proto_s[f + 0]; m[0] = (bf16_t)__builtin_amdgcn_exp2f(-d * d * ivar_s[f + 0]);
      d = x0.y - proto_s[f + 1]; m[1] = (bf16_t)__builtin_amdgcn_exp2f(-d * d * ivar_s[f + 1]);
      d = x0.z - proto_s[f + 2]; m[2] = (bf16_t)__builtin_amdgcn_exp2f(-d * d * ivar_s[f + 2]);
      d = x0.w - proto_s[f + 3]; m[3] = (bf16_t)__builtin_amdgcn_exp2f(-d * d * ivar_s[f + 3]);
      d = x1.x - proto_s[f + 4]; m[4] = (bf16_t)__builtin_amdgcn_exp2f(-d * d * ivar_s[f + 4]);
      d = x1.y - proto_s[f + 5]; m[5] = (bf16_t)__builtin_amdgcn_exp2f(-d * d * ivar_s[f + 5]);
      d = x1.z - proto_s[f + 6]; m[6] = (bf16_t)__builtin_amdgcn_exp2f(-d * d * ivar_s[f + 6]);
      d = x1.w - proto_s[f + 7]; m[7] = (bf16_t)__builtin_amdgcn_exp2f(-d * d * ivar_s[f + 7]);
      *(bf16x8*)(mrow + ((f * 2) ^ sw)) = m;
    }
  }
  __syncthreads();

  // GEMM1: h1T[128][128] = Wf1 @ memT. wave w -> m-tile w, all 8 n-tiles.
  f32x4 acc[8] = {};
  #pragma unroll
  for (int ks = 0; ks < 8; ++ks) {
    bf16x8 a = *(const bf16x8*)(Wf1p + (((ks * 8 + w) * 64 + lane)) * 8);
    #pragma unroll
    for (int j = 0; j < 8; ++j) {
      bf16x8 bb = lfrag16(fs_lds, 512, j * 16, ks * 32, lane);
      acc[j] = mfma16(a, bb, acc[j]);
    }
  }
  __syncthreads();   // mem dead -> overlay h1T [128 b][128 h] swz16 in [0,32768)

  {
    const int hb = w * 16 + ((lane >> 4) << 2);
    f32x4 bias = *(const f32x4*)(bf1g + hb);
    #pragma unroll
    for (int j = 0; j < 8; ++j) {
      const int b = j * 16 + (lane & 15);
      bf16x4 o;
      #pragma unroll
      for (int q = 0; q < 4; ++q)
        o[q] = (bf16_t)fmaxf(acc[j][q] + bias[q], 0.f);
      *(bf16x4*)(fs_lds + b * 256 + ((hb * 2) ^ ((b & 15) << 4))) = o;
    }
  }
  __syncthreads();

  // GEMM2: h2T[32][128] = Wf2 @ h1T. wave: m = w>>2, n-tiles (w&3)*2+{0,1}.
  {
    const int m = w >> 2;
    f32x4 acc2[2] = {};
    #pragma unroll
    for (int ks = 0; ks < 4; ++ks) {
      bf16x8 a = *(const bf16x8*)(Wf2p + (((ks * 2 + m) * 64 + lane)) * 8);
      #pragma unroll
      for (int j = 0; j < 2; ++j) {
        bf16x8 bb = lfrag16(fs_lds, 256, ((w & 3) * 2 + j) * 16, ks * 32, lane);
        acc2[j] = mfma16(a, bb, acc2[j]);
      }
    }
    const int p0 = m * 16 + ((lane >> 4) << 2);
    f32x4 bias = *(const f32x4*)(bf2g + p0);
    #pragma unroll
    for (int j = 0; j < 2; ++j) {
      const int b = ((w & 3) * 2 + j) * 16 + (lane & 15);
      #pragma unroll
      for (int q = 0; q < 4; ++q)
        h2t[(p0 + q) * 128 + b] = (bf16_t)fmaxf(acc2[j][q] + bias[q], 0.f);
    }
  }
  __syncthreads();

  if (tid < 128) {
    float s = bf3g[0];
    #pragma unroll
    for (int p = 0; p < H2N; ++p) s += (float)h2t[p * 128 + tid] * Wf3g[p];
    fsini[(long)(b0 + tid) * RN + r] = fmaxf(s, 0.f);
  }
}

// ---------------- K3: consequent chain, 2 rules/block, data staged once. 4-bit swizzle. ----------------
__global__ __launch_bounds__(512) void k3_cons(
    const bf16_t* __restrict__ datab,
    const bf16_t* __restrict__ Wc1p, const bf16_t* __restrict__ Wc2p, const bf16_t* __restrict__ Wc3p,
    const float* __restrict__ bc1, const float* __restrict__ bc2, const float* __restrict__ bc3,
    float* __restrict__ c3buf)
{
  __shared__ __attribute__((aligned(16))) char smem[73728];
  char* d_lds  = smem;           // [64][256] bf16 swz16 (persistent)
  char* c1_lds = smem + 32768;   // [64 b][256 g1] bf16 swz16
  char* c2_lds = smem + 65536;   // [64 b][64 g2] bf16 swz8 (128B rows: 4-bit would overflow)

  const int bid = blockIdx.x;
  const int xcd = bid & 7;
  const int kk  = bid >> 3;
  const int rp  = xcd * 2 + (kk >> 8);
  const int b0  = (kk & 255) << 6;

  const int tid = threadIdx.x;
  const int lane = tid & 63;
  const int w   = tid >> 6;

  { // stage data tile once; swz16 write
    const int row = tid >> 3;
    const int e0  = (tid & 7) << 5;
    const bf16_t* sp = datab + (long)(b0 + row) * FN + e0;
    char* drow = d_lds + row * 512;
    const int sw = (row & 15) << 4;
    #pragma unroll
    for (int i = 0; i < 4; ++i) {
      bf16x8 v = *(const bf16x8*)(sp + i * 8);
      *(bf16x8*)(drow + (((e0 + i * 8) * 2) ^ sw)) = v;
    }
  }
  __syncthreads();

  for (int rr = 0; rr < 2; ++rr) {
    const int r = rp * 2 + rr;

    // GEMM1: c1T[256][64]. wave w -> m-tiles {2w,2w+1}, all 4 n-tiles.
    const bf16_t* W1 = Wc1p + (long)r * G1N * FN;
    f32x4 acc[2][4] = {};
    #pragma unroll
    for (int ks = 0; ks < 8; ++ks) {
      bf16x8 a[2], bb[4];
      #pragma unroll
      for (int i = 0; i < 2; ++i)
        a[i] = *(const bf16x8*)(W1 + (((ks * 16 + w * 2 + i) * 64 + lane)) * 8);
      #pragma unroll
      for (int j = 0; j < 4; ++j)
        bb[j] = lfrag16(d_lds, 512, j * 16, ks * 32, lane);
      #pragma unroll
      for (int i = 0; i < 2; ++i)
        #pragma unroll
        for (int j = 0; j < 4; ++j)
          acc[i][j] = mfma16(a[i], bb[j], acc[i][j]);
    }
    #pragma unroll
    for (int i = 0; i < 2; ++i) {
      const int g1b = (w * 2 + i) * 16 + ((lane >> 4) << 2);
      f32x4 bias = *(const f32x4*)(bc1 + r * G1N + g1b);
      #pragma unroll
      for (int j = 0; j < 4; ++j) {
        const int b = j * 16 + (lane & 15);
        bf16x4 o;
        #pragma unroll
        for (int q = 0; q < 4; ++q)
          o[q] = (bf16_t)elu_f(acc[i][j][q] + bias[q]);
        *(bf16x4*)(c1_lds + b * 512 + ((g1b * 2) ^ ((b & 15) << 4))) = o;
      }
    }
    __syncthreads();   // c1T ready

    // GEMM2: c2T[64][64]. wave: m = w>>1, n-tiles {2(w&1), 2(w&1)+1}.
    {
      const int m2 = w >> 1;
      const int n2 = w & 1;
      const bf16_t* W2 = Wc2p + (long)r * G2N * G1N;
      f32x4 acc2[2] = {};
      #pragma unroll
      for (int ks = 0; ks < 8; ++ks) {
        bf16x8 a = *(const bf16x8*)(W2 + (((ks * 4 + m2) * 64 + lane)) * 8);
        #pragma unroll
        for (int j = 0; j < 2; ++j) {
          bf16x8 bb = lfrag16(c1_lds, 512, (n2 * 2 + j) * 16, ks * 32, lane);
          acc2[j] = mfma16(a, bb, acc2[j]);
        }
      }
      const int g2b = m2 * 16 + ((lane >> 4) << 2);
      f32x4 bias = *(const f32x4*)(bc2 + r * G2N + g2b);
      #pragma unroll
      for (int j = 0; j < 2; ++j) {
        const int b = (n2 * 2 + j) * 16 + (lane & 15);
        bf16x4 o;
        #pragma unroll
        for (int q = 0; q < 4; ++q)
          o[q] = (bf16_t)elu_f(acc2[j][q] + bias[q]);
        *(bf16x4*)(c2_lds + b * 128 + ((g2b * 2) ^ ((b & 7) << 4))) = o;
      }
    }
    __syncthreads();   // c2T ready

    // GEMM3: c3T[16][64]. 4 n-tiles; waves 0-3. K=64. (c2T is 3-bit swizzled.)
    if (w < 4) {
      const bf16_t* W3 = Wc3p + (long)r * CN * G2N;
      f32x4 acc3 = {};
      #pragma unroll
      for (int ks = 0; ks < 2; ++ks) {
        bf16x8 a = *(const bf16x8*)(W3 + (((long)ks * 64 + lane)) * 8);
        bf16x8 bb = lfrag(c2_lds, 128, w * 16, ks * 32, lane);
        acc3 = mfma16(a, bb, acc3);
      }
      const int c0 = ((lane >> 4) << 2);
      const int b  = w * 16 + (lane & 15);
      f32x4 bias = *(const f32x4*)(bc3 + r * CN + c0);
      f32x4 o;
      #pragma unroll
      for (int q = 0; q < 4; ++q) o[q] = fmaxf(acc3[q] + bias[q], 0.f);
      *(f32x4*)(c3buf + ((long)r * BN + b0 + b) * CN + c0) = o;
    }
    __syncthreads();   // c1T/c2T free for next rule
  }
}

// k4: softmax over rules + weighted combine + fire output.
__global__ __launch_bounds__(256) void k4_out(const float* __restrict__ fsini,
                                              const float* __restrict__ c3buf,
                                              float* __restrict__ out,
                                              float* __restrict__ fire_g)
{
  int t = blockIdx.x * 256 + threadIdx.x;   // over B*C/4
  int b = t >> 2, c4 = (t & 3) << 2;
  float v[RN];
  const float4* p = (const float4*)(fsini + (long)b * RN);
  #pragma unroll
  for (int i = 0; i < RN / 4; ++i) {
    float4 x = p[i];
    v[4 * i] = x.x; v[4 * i + 1] = x.y; v[4 * i + 2] = x.z; v[4 * i + 3] = x.w;
  }
  float m = v[0];
  #pragma unroll
  for (int i = 1; i < RN; ++i) m = fmaxf(m, v[i]);
  float s = 0.f;
  #pragma unroll
  for (int i = 0; i < RN; ++i) { v[i] = expf(v[i] - m); s += v[i]; }
  float inv = 1.f / s;
  #pragma unroll
  for (int i = 0; i < RN; ++i) v[i] *= inv;

  f32x4 acc = {};
  #pragma unroll
  for (int rrr = 0; rrr < RN; ++rrr) {
    f32x4 c = *(const f32x4*)(c3buf + ((long)rrr * BN + b) * CN + c4);
    acc += v[rrr] * c;
  }
  *(f32x4*)(out + (long)b * CN + c4) = acc;

  if (c4 == 0) {
    float4* o = (float4*)(fire_g + (long)b * RN);
    #pragma unroll
    for (int i = 0; i < RN / 4; ++i) {
      float4 x; x.x = v[4 * i]; x.y = v[4 * i + 1]; x.z = v[4 * i + 2]; x.w = v[4 * i + 3];
      o[i] = x;
    }
  }
}

extern "C" void kernel_launch(void* const* d_in, const int* in_sizes, int n_in,
                              void* d_out, int out_size, void* d_ws, size_t ws_size,
                              hipStream_t stream) {
  const float* data = (const float*)d_in[0];
  const float* proto = (const float*)d_in[1];
  const float* var  = (const float*)d_in[2];
  const float* Wf1  = (const float*)d_in[3];
  const float* bf1  = (const float*)d_in[4];
  const float* Wf2  = (const float*)d_in[5];
  const float* bf2  = (const float*)d_in[6];
  const float* Wf3  = (const float*)d_in[7];
  const float* bf3  = (const float*)d_in[8];
  const float* Wc1  = (const float*)d_in[9];
  const float* bc1  = (const float*)d_in[10];
  const float* Wc2  = (const float*)d_in[11];
  const float* bc2  = (const float*)d_in[12];
  const float* Wc3  = (const float*)d_in[13];
  const float* bc3  = (const float*)d_in[14];

  char* ws = (char*)d_ws;
  bf16_t* datab = (bf16_t*)(ws + OFF_DATA);
  bf16_t* Wf1p  = (bf16_t*)(ws + OFF_WF1);
  bf16_t* Wf2p  = (bf16_t*)(ws + OFF_WF2);
  bf16_t* Wc1p  = (bf16_t*)(ws + OFF_WC1);
  bf16_t* Wc2p  = (bf16_t*)(ws + OFF_WC2);
  bf16_t* Wc3p  = (bf16_t*)(ws + OFF_WC3);
  float*  fsini = (float*)(ws + OFF_FSINI);
  float*  c3buf = (float*)(ws + OFF_C3);

  float* out  = (float*)d_out;               // [B][C]
  float* fire = out + (long)BN * CN;         // [B][R]

  k0_pack<<<G_TOTAL / 256, 256, 0, stream>>>(data, Wf1, Wf2, Wc1, Wc2, Wc3, ws);
  k3_cons<<<16 * (BN / 64) / 2 * 2, 512, 0, stream>>>(datab, Wc1p, Wc2p, Wc3p,
                                                      bc1, bc2, bc3, c3buf);
  k1_fs<<<RN * (BN / 128), 512, 0, stream>>>(data, proto, var, bf1, bf2, Wf3, bf3,
                                             Wf1p, Wf2p, fsini);
  k4_out<<<(BN * CN / 4) / 256, 256, 0, stream>>>(fsini, c3buf, out, fire);
}

// Round 21
// 241.924 us; speedup vs baseline: 1.6662x; 1.0278x over previous
//
#include <hip/hip_runtime.h>
#include <hip/hip_bf16.h>

// Problem dims
#define BN 16384
#define FN 256
#define RN 32
#define CN 16
#define H1N 128
#define H2N 32
#define G1N 256
#define G2N 64

typedef __bf16 bf16_t;
typedef __bf16 bf16x8 __attribute__((ext_vector_type(8)));
typedef __bf16 bf16x4 __attribute__((ext_vector_type(4)));
typedef float f32x4 __attribute__((ext_vector_type(4)));

// ---- workspace byte offsets ----
#define OFF_DATA   0UL
#define OFF_WF1    8388608UL
#define OFF_WF2    8454144UL
#define OFF_WC1    8462336UL
#define OFF_WC2    12656640UL
#define OFF_WC3    13705216UL
#define OFF_FSINI  13770752UL
#define OFF_C3     15867904UL

__device__ __forceinline__ f32x4 mfma16(bf16x8 a, bf16x8 b, f32x4 c) {
  return __builtin_amdgcn_mfma_f32_16x16x32_bf16(a, b, c, 0, 0, 0);
}

__device__ __forceinline__ float elu_f(float v) {
  float e = __builtin_amdgcn_exp2f(v * 1.44269504f) - 1.0f;
  return v > 0.f ? v : e;
}

// B-frag, 3-bit XOR swizzle ((row&7)<<4) — for 128B-row tiles only (c2T).
__device__ __forceinline__ bf16x8 lfrag(const char* base, int strideB, int n0, int k0, int lane) {
  int row = n0 + (lane & 15);
  int off = (k0 * 2 + ((lane >> 4) << 4)) ^ ((row & 7) << 4);
  return *(const bf16x8*)(base + row * strideB + off);
}

// B-frag, 4-bit XOR swizzle ((row&15)<<4) — for >=256B-row tiles.
__device__ __forceinline__ bf16x8 lfrag16(const char* base, int strideB, int n0, int k0, int lane) {
  int row = n0 + (lane & 15);
  int off = (k0 * 2 + ((lane >> 4) << 4)) ^ ((row & 15) << 4);
  return *(const bf16x8*)(base + row * strideB + off);
}

// Pack W[(r,)n,k] fp32 -> 16x16x32 fragment order bf16.
__device__ __forceinline__ void pack_frag8(const float* __restrict__ src, bf16_t* __restrict__ dst,
                                           int NT, int KS, int g) {
  int per = NT * KS * 64;
  int r = g / per;
  int local = g - r * per;
  int lane = local & 63;
  int fr = local >> 6;
  int ks = fr / NT;
  int nt = fr - ks * NT;
  int N = NT * 16, K = KS * 32;
  int n = nt * 16 + (lane & 15);
  int k = ks * 32 + ((lane >> 4) << 3);
  const float* s = src + (long)r * N * K + (long)n * K + k;
  float4 a = *(const float4*)s;
  float4 b = *(const float4*)(s + 4);
  bf16x8 o;
  o[0] = (bf16_t)a.x; o[1] = (bf16_t)a.y; o[2] = (bf16_t)a.z; o[3] = (bf16_t)a.w;
  o[4] = (bf16_t)b.x; o[5] = (bf16_t)b.y; o[6] = (bf16_t)b.z; o[7] = (bf16_t)b.w;
  *(bf16x8*)(dst + (long)g * 8) = o;
}

#define G_DATA 524288
#define G_WC1  262144
#define G_WC2  65536
#define G_WF1  4096
#define G_WC3  4096
#define G_WF2  512
#define G_TOTAL (G_DATA + G_WC1 + G_WC2 + G_WF1 + G_WC3 + G_WF2)

__global__ __launch_bounds__(256) void k0_pack(
    const float* __restrict__ data, const float* __restrict__ Wf1, const float* __restrict__ Wf2,
    const float* __restrict__ Wc1, const float* __restrict__ Wc2, const float* __restrict__ Wc3,
    char* __restrict__ ws)
{
  int g = blockIdx.x * 256 + threadIdx.x;
  if (g < G_DATA) {
    const float* s = data + (long)g * 8;
    float4 a = *(const float4*)s, b = *(const float4*)(s + 4);
    bf16x8 o;
    o[0] = (bf16_t)a.x; o[1] = (bf16_t)a.y; o[2] = (bf16_t)a.z; o[3] = (bf16_t)a.w;
    o[4] = (bf16_t)b.x; o[5] = (bf16_t)b.y; o[6] = (bf16_t)b.z; o[7] = (bf16_t)b.w;
    *(bf16x8*)((bf16_t*)(ws + OFF_DATA) + (long)g * 8) = o;
    return;
  }
  g -= G_DATA;
  if (g < G_WC1) { pack_frag8(Wc1, (bf16_t*)(ws + OFF_WC1), 16, 8, g); return; }
  g -= G_WC1;
  if (g < G_WC2) { pack_frag8(Wc2, (bf16_t*)(ws + OFF_WC2), 4, 8, g); return; }
  g -= G_WC2;
  if (g < G_WF1) { pack_frag8(Wf1, (bf16_t*)(ws + OFF_WF1), 8, 8, g); return; }
  g -= G_WF1;
  if (g < G_WC3) { pack_frag8(Wc3, (bf16_t*)(ws + OFF_WC3), 1, 2, g); return; }
  g -= G_WC3;
  if (g < G_WF2) { pack_frag8(Wf2, (bf16_t*)(ws + OFF_WF2), 2, 4, g); return; }
}

// ---------------- K1: FS chain, per (rule, 128-row tile). ----------------
// GEMM1 wave split 4m x 2n: B-DS-reads halved (512->256/block); A-loads x2 (L2-resident Wf1).
__global__ __launch_bounds__(512) void k1_fs(
    const float* __restrict__ data, const float* __restrict__ proto, const float* __restrict__ var,
    const float* __restrict__ bf1g, const float* __restrict__ bf2g,
    const float* __restrict__ Wf3g, const float* __restrict__ bf3g,
    const bf16_t* __restrict__ Wf1p, const bf16_t* __restrict__ Wf2p,
    float* __restrict__ fsini)
{
  __shared__ __attribute__((aligned(16))) char smem[75776];
  char* fs_lds   = smem;                      // mem [128][256] bf16 swz16; h1T [128][128] swz16 overlays
  bf16_t* h2t    = (bf16_t*)(smem + 65536);   // [32][128]
  float* proto_s = (float*)(smem + 73728);
  float* ivar_s  = (float*)(smem + 74752);

  const int bid = blockIdx.x;
  const int r   = bid >> 7;
  const int b0  = (bid & 127) << 7;
  const int tid = threadIdx.x;
  const int lane = tid & 63;
  const int w   = tid >> 6;

  if (tid < FN) {
    proto_s[tid] = proto[r * FN + tid];
    float v = var[r * FN + tid];
    v = fminf(fmaxf(v, 1e-4f), 0.1f);
    ivar_s[tid] = 1.4426950408889634f * 0.5f / (v * v);
  }
  __syncthreads();

  { // membership: 4 threads/row, 64 feats each; swz16 write
    const int row = tid >> 2;
    const int f0  = (tid & 3) << 6;
    const float* dp = data + (long)(b0 + row) * FN + f0;
    char* mrow = fs_lds + row * 512;
    const int sw = (row & 15) << 4;
    #pragma unroll
    for (int i = 0; i < 8; ++i) {
      const int f = f0 + i * 8;
      float4 x0 = *(const float4*)(dp + i * 8);
      float4 x1 = *(const float4*)(dp + i * 8 + 4);
      bf16x8 m; float d;
      d = x0.x - proto_s[f + 0]; m[0] = (bf16_t)__builtin_amdgcn_exp2f(-d * d * ivar_s[f + 0]);
      d = x0.y - proto_s[f + 1]; m[1] = (bf16_t)__builtin_amdgcn_exp2f(-d * d * ivar_s[f + 1]);
      d = x0.z - proto_s[f + 2]; m[2] = (bf16_t)__builtin_amdgcn_exp2f(-d * d * ivar_s[f + 2]);
      d = x0.w - proto_s[f + 3]; m[3] = (bf16_t)__builtin_amdgcn_exp2f(-d * d * ivar_s[f + 3]);
      d = x1.x - proto_s[f + 4]; m[4] = (bf16_t)__builtin_amdgcn_exp2f(-d * d * ivar_s[f + 4]);
      d = x1.y - proto_s[f + 5]; m[5] = (bf16_t)__builtin_amdgcn_exp2f(-d * d * ivar_s[f + 5]);
      d = x1.z - proto_s[f + 6]; m[6] = (bf16_t)__builtin_amdgcn_exp2f(-d * d * ivar_s[f + 6]);
      d = x1.w - proto_s[f + 7]; m[7] = (bf16_t)__builtin_amdgcn_exp2f(-d * d * ivar_s[f + 7]);
      *(bf16x8*)(mrow + ((f * 2) ^ sw)) = m;
    }
  }
  __syncthreads();

  // GEMM1: h1T[128][128] = Wf1 @ memT. 8m x 8n tiles; wave (wm=w>>1, wn=w&1):
  // m-tiles {2wm, 2wm+1}, n-tiles {4wn..4wn+3}. B-DS-reads 4/ks/wave (was 8).
  const int wm = w >> 1;
  const int wn = w & 1;
  f32x4 acc[2][4] = {};
  #pragma unroll
  for (int ks = 0; ks < 8; ++ks) {
    bf16x8 a[2], bb[4];
    #pragma unroll
    for (int i = 0; i < 2; ++i)
      a[i] = *(const bf16x8*)(Wf1p + (((ks * 8 + wm * 2 + i) * 64 + lane)) * 8);
    #pragma unroll
    for (int j = 0; j < 4; ++j)
      bb[j] = lfrag16(fs_lds, 512, (wn * 4 + j) * 16, ks * 32, lane);
    #pragma unroll
    for (int i = 0; i < 2; ++i)
      #pragma unroll
      for (int j = 0; j < 4; ++j)
        acc[i][j] = mfma16(a[i], bb[j], acc[i][j]);
  }
  __syncthreads();   // mem dead -> overlay h1T [128 b][128 h] swz16 in [0,32768)

  #pragma unroll
  for (int i = 0; i < 2; ++i) {
    const int hb = (wm * 2 + i) * 16 + ((lane >> 4) << 2);
    f32x4 bias = *(const f32x4*)(bf1g + hb);
    #pragma unroll
    for (int j = 0; j < 4; ++j) {
      const int b = (wn * 4 + j) * 16 + (lane & 15);
      bf16x4 o;
      #pragma unroll
      for (int q = 0; q < 4; ++q)
        o[q] = (bf16_t)fmaxf(acc[i][j][q] + bias[q], 0.f);
      *(bf16x4*)(fs_lds + b * 256 + ((hb * 2) ^ ((b & 15) << 4))) = o;
    }
  }
  __syncthreads();

  // GEMM2: h2T[32][128] = Wf2 @ h1T. wave: m = w>>2, n-tiles (w&3)*2+{0,1}.
  {
    const int m = w >> 2;
    f32x4 acc2[2] = {};
    #pragma unroll
    for (int ks = 0; ks < 4; ++ks) {
      bf16x8 a = *(const bf16x8*)(Wf2p + (((ks * 2 + m) * 64 + lane)) * 8);
      #pragma unroll
      for (int j = 0; j < 2; ++j) {
        bf16x8 bb = lfrag16(fs_lds, 256, ((w & 3) * 2 + j) * 16, ks * 32, lane);
        acc2[j] = mfma16(a, bb, acc2[j]);
      }
    }
    const int p0 = m * 16 + ((lane >> 4) << 2);
    f32x4 bias = *(const f32x4*)(bf2g + p0);
    #pragma unroll
    for (int j = 0; j < 2; ++j) {
      const int b = ((w & 3) * 2 + j) * 16 + (lane & 15);
      #pragma unroll
      for (int q = 0; q < 4; ++q)
        h2t[(p0 + q) * 128 + b] = (bf16_t)fmaxf(acc2[j][q] + bias[q], 0.f);
    }
  }
  __syncthreads();

  if (tid < 128) {
    float s = bf3g[0];
    #pragma unroll
    for (int p = 0; p < H2N; ++p) s += (float)h2t[p * 128 + tid] * Wf3g[p];
    fsini[(long)(b0 + tid) * RN + r] = fmaxf(s, 0.f);
  }
}

// ---------------- K3: consequent chain, 4 rules per block, data staged once ----------------
// Grid 2048 blocks; xcd = quad of rules (weights per XCD ~650KB, fully L2-warm).
__global__ __launch_bounds__(512) void k3_cons(
    const bf16_t* __restrict__ datab,
    const bf16_t* __restrict__ Wc1p, const bf16_t* __restrict__ Wc2p, const bf16_t* __restrict__ Wc3p,
    const float* __restrict__ bc1, const float* __restrict__ bc2, const float* __restrict__ bc3,
    float* __restrict__ c3buf)
{
  __shared__ __attribute__((aligned(16))) char smem[73728];
  char* d_lds  = smem;           // [64][256] bf16 swz16 (persistent across 4 rules)
  char* c1_lds = smem + 32768;   // [64 b][256 g1] bf16 swz16
  char* c2_lds = smem + 65536;   // [64 b][64 g2] bf16 swz8

  const int bid  = blockIdx.x;         // 0..2047
  const int quad = bid & 7;            // = XCD; rules quad*4 .. quad*4+3
  const int b0   = (bid >> 3) << 6;    // 0..255 tiles of 64 rows

  const int tid = threadIdx.x;
  const int lane = tid & 63;
  const int w   = tid >> 6;

  { // stage data tile once; swz16 write
    const int row = tid >> 3;
    const int e0  = (tid & 7) << 5;
    const bf16_t* sp = datab + (long)(b0 + row) * FN + e0;
    char* drow = d_lds + row * 512;
    const int sw = (row & 15) << 4;
    #pragma unroll
    for (int i = 0; i < 4; ++i) {
      bf16x8 v = *(const bf16x8*)(sp + i * 8);
      *(bf16x8*)(drow + (((e0 + i * 8) * 2) ^ sw)) = v;
    }
  }
  __syncthreads();

  for (int rr = 0; rr < 4; ++rr) {
    const int r = quad * 4 + rr;

    // GEMM1: c1T[256][64]. wave w -> m-tiles {2w,2w+1}, all 4 n-tiles.
    const bf16_t* W1 = Wc1p + (long)r * G1N * FN;
    f32x4 acc[2][4] = {};
    #pragma unroll
    for (int ks = 0; ks < 8; ++ks) {
      bf16x8 a[2], bb[4];
      #pragma unroll
      for (int i = 0; i < 2; ++i)
        a[i] = *(const bf16x8*)(W1 + (((ks * 16 + w * 2 + i) * 64 + lane)) * 8);
      #pragma unroll
      for (int j = 0; j < 4; ++j)
        bb[j] = lfrag16(d_lds, 512, j * 16, ks * 32, lane);
      #pragma unroll
      for (int i = 0; i < 2; ++i)
        #pragma unroll
        for (int j = 0; j < 4; ++j)
          acc[i][j] = mfma16(a[i], bb[j], acc[i][j]);
    }
    #pragma unroll
    for (int i = 0; i < 2; ++i) {
      const int g1b = (w * 2 + i) * 16 + ((lane >> 4) << 2);
      f32x4 bias = *(const f32x4*)(bc1 + r * G1N + g1b);
      #pragma unroll
      for (int j = 0; j < 4; ++j) {
        const int b = j * 16 + (lane & 15);
        bf16x4 o;
        #pragma unroll
        for (int q = 0; q < 4; ++q)
          o[q] = (bf16_t)elu_f(acc[i][j][q] + bias[q]);
        *(bf16x4*)(c1_lds + b * 512 + ((g1b * 2) ^ ((b & 15) << 4))) = o;
      }
    }
    __syncthreads();   // c1T ready

    // GEMM2: c2T[64][64]. wave: m = w>>1, n-tiles {2(w&1), 2(w&1)+1}.
    {
      const int m2 = w >> 1;
      const int n2 = w & 1;
      const bf16_t* W2 = Wc2p + (long)r * G2N * G1N;
      f32x4 acc2[2] = {};
      #pragma unroll
      for (int ks = 0; ks < 8; ++ks) {
        bf16x8 a = *(const bf16x8*)(W2 + (((ks * 4 + m2) * 64 + lane)) * 8);
        #pragma unroll
        for (int j = 0; j < 2; ++j) {
          bf16x8 bb = lfrag16(c1_lds, 512, (n2 * 2 + j) * 16, ks * 32, lane);
          acc2[j] = mfma16(a, bb, acc2[j]);
        }
      }
      const int g2b = m2 * 16 + ((lane >> 4) << 2);
      f32x4 bias = *(const f32x4*)(bc2 + r * G2N + g2b);
      #pragma unroll
      for (int j = 0; j < 2; ++j) {
        const int b = (n2 * 2 + j) * 16 + (lane & 15);
        bf16x4 o;
        #pragma unroll
        for (int q = 0; q < 4; ++q)
          o[q] = (bf16_t)elu_f(acc2[j][q] + bias[q]);
        *(bf16x4*)(c2_lds + b * 128 + ((g2b * 2) ^ ((b & 7) << 4))) = o;
      }
    }
    __syncthreads();   // c2T ready

    // GEMM3: c3T[16][64]. 4 n-tiles; waves 0-3. K=64.
    if (w < 4) {
      const bf16_t* W3 = Wc3p + (long)r * CN * G2N;
      f32x4 acc3 = {};
      #pragma unroll
      for (int ks = 0; ks < 2; ++ks) {
        bf16x8 a = *(const bf16x8*)(W3 + (((long)ks * 64 + lane)) * 8);
        bf16x8 bb = lfrag(c2_lds, 128, w * 16, ks * 32, lane);
        acc3 = mfma16(a, bb, acc3);
      }
      const int c0 = ((lane >> 4) << 2);
      const int b  = w * 16 + (lane & 15);
      f32x4 bias = *(const f32x4*)(bc3 + r * CN + c0);
      f32x4 o;
      #pragma unroll
      for (int q = 0; q < 4; ++q) o[q] = fmaxf(acc3[q] + bias[q], 0.f);
      *(f32x4*)(c3buf + ((long)r * BN + b0 + b) * CN + c0) = o;
    }
    __syncthreads();   // c1T/c2T free for next rule
  }
}

// k4: softmax over rules + weighted combine + fire output.
__global__ __launch_bounds__(256) void k4_out(const float* __restrict__ fsini,
                                              const float* __restrict__ c3buf,
                                              float* __restrict__ out,
                                              float* __restrict__ fire_g)
{
  int t = blockIdx.x * 256 + threadIdx.x;   // over B*C/4
  int b = t >> 2, c4 = (t & 3) << 2;
  float v[RN];
  const float4* p = (const float4*)(fsini + (long)b * RN);
  #pragma unroll
  for (int i = 0; i < RN / 4; ++i) {
    float4 x = p[i];
    v[4 * i] = x.x; v[4 * i + 1] = x.y; v[4 * i + 2] = x.z; v[4 * i + 3] = x.w;
  }
  float m = v[0];
  #pragma unroll
  for (int i = 1; i < RN; ++i) m = fmaxf(m, v[i]);
  float s = 0.f;
  #pragma unroll
  for (int i = 0; i < RN; ++i) { v[i] = expf(v[i] - m); s += v[i]; }
  float inv = 1.f / s;
  #pragma unroll
  for (int i = 0; i < RN; ++i) v[i] *= inv;

  f32x4 acc = {};
  #pragma unroll
  for (int rrr = 0; rrr < RN; ++rrr) {
    f32x4 c = *(const f32x4*)(c3buf + ((long)rrr * BN + b) * CN + c4);
    acc += v[rrr] * c;
  }
  *(f32x4*)(out + (long)b * CN + c4) = acc;

  if (c4 == 0) {
    float4* o = (float4*)(fire_g + (long)b * RN);
    #pragma unroll
    for (int i = 0; i < RN / 4; ++i) {
      float4 x; x.x = v[4 * i]; x.y = v[4 * i + 1]; x.z = v[4 * i + 2]; x.w = v[4 * i + 3];
      o[i] = x;
    }
  }
}

extern "C" void kernel_launch(void* const* d_in, const int* in_sizes, int n_in,
                              void* d_out, int out_size, void* d_ws, size_t ws_size,
                              hipStream_t stream) {
  const float* data = (const float*)d_in[0];
  const float* proto = (const float*)d_in[1];
  const float* var  = (const float*)d_in[2];
  const float* Wf1  = (const float*)d_in[3];
  const float* bf1  = (const float*)d_in[4];
  const float* Wf2  = (const float*)d_in[5];
  const float* bf2  = (const float*)d_in[6];
  const float* Wf3  = (const float*)d_in[7];
  const float* bf3  = (const float*)d_in[8];
  const float* Wc1  = (const float*)d_in[9];
  const float* bc1  = (const float*)d_in[10];
  const float* Wc2  = (const float*)d_in[11];
  const float* bc2  = (const float*)d_in[12];
  const float* Wc3  = (const float*)d_in[13];
  const float* bc3  = (const float*)d_in[14];

  char* ws = (char*)d_ws;
  bf16_t* datab = (bf16_t*)(ws + OFF_DATA);
  bf16_t* Wf1p  = (bf16_t*)(ws + OFF_WF1);
  bf16_t* Wf2p  = (bf16_t*)(ws + OFF_WF2);
  bf16_t* Wc1p  = (bf16_t*)(ws + OFF_WC1);
  bf16_t* Wc2p  = (bf16_t*)(ws + OFF_WC2);
  bf16_t* Wc3p  = (bf16_t*)(ws + OFF_WC3);
  float*  fsini = (float*)(ws + OFF_FSINI);
  float*  c3buf = (float*)(ws + OFF_C3);

  float* out  = (float*)d_out;               // [B][C]
  float* fire = out + (long)BN * CN;         // [B][R]

  k0_pack<<<G_TOTAL / 256, 256, 0, stream>>>(data, Wf1, Wf2, Wc1, Wc2, Wc3, ws);
  k3_cons<<<8 * (BN / 64), 512, 0, stream>>>(datab, Wc1p, Wc2p, Wc3p,
                                             bc1, bc2, bc3, c3buf);
  k1_fs<<<RN * (BN / 128), 512, 0, stream>>>(data, proto, var, bf1, bf2, Wf3, bf3,
                                             Wf1p, Wf2p, fsini);
  k4_out<<<(BN * CN / 4) / 256, 256, 0, stream>>>(fsini, c3buf, out, fire);
}